// Round 6
// baseline (789.551 us; speedup 1.0000x reference)
//
#include <hip/hip_runtime.h>
#include <hip/hip_cooperative_groups.h>
#include <stdint.h>

namespace cg = cooperative_groups;

#define DEVI __device__ __forceinline__
typedef unsigned short u16;
typedef __attribute__((ext_vector_type(8))) short s16x8;
typedef __attribute__((ext_vector_type(4))) float f32x4;

typedef __attribute__((address_space(1))) void as1_void;
typedef __attribute__((address_space(3))) void as3_void;

DEVI u16 f2b(float f){
  union { float f; uint32_t u; } x; x.f = f;
  return (u16)((x.u + 0x7fffu + ((x.u >> 16) & 1u)) >> 16);
}
DEVI float b2f(u16 u){
  union { uint32_t u; float f; } x; x.u = ((uint32_t)u) << 16;
  return x.f;
}
DEVI void gload16(const void* g, void* l){
  __builtin_amdgcn_global_load_lds((as1_void*)g, (as3_void*)l, 16, 0, 0);
}
DEVI f32x4 MFMA(s16x8 a, s16x8 b, f32x4 c){
  return __builtin_amdgcn_mfma_f32_16x16x32_bf16(a, b, c, 0, 0, 0);
}

struct MP {
  const float *Q, *K, *V, *Wq, *bq, *Wk, *bk, *Wv, *bv, *Wo, *bo;
  u16 *Qb, *Kb, *Vb, *WqT, *WkT, *WvT, *WoT, *qw, *kw, *vT, *cc;
  float *attn, *out;
};

// 64 KB LDS union -> 2 blocks/CU co-resident (128 of 160 KB)
union SMem {
  float t[64][65];                                       // prep transpose
  struct { u16 A[2 * 128 * 64]; u16 B[2 * 128 * 64]; } g; // gemm (64 KB)
  struct { u16 q[64 * 64]; u16 k[128 * 64];
           u16 v[64 * 128]; u16 p[64 * 128]; } at;        // attn (56 KB)
};

// ---------------- phase 1 unit: convert (12288) + transpose (1024) ----------
DEVI void prep_unit(const MP& P, SMem& sm, int u){
  const int tid = threadIdx.x;
  if(u < 12288){
    int tno = u >> 12, blk = u & 4095;
    const float* s = (tno == 0) ? P.Q : (tno == 1) ? P.K : P.V;
    u16* d = (tno == 0) ? P.Qb : (tno == 1) ? P.Kb : P.Vb;
    int i = (blk * 256 + tid) * 4;
    float4 v = *(const float4*)(s + i);
    ushort4 o;
    o.x = f2b(v.x); o.y = f2b(v.y); o.z = f2b(v.z); o.w = f2b(v.w);
    *(ushort4*)(d + i) = o;
  } else {
    int j = u - 12288;
    const float* src; u16* dst; int C, r0, c0;
    if(j < 768){
      int tno = j >> 8, rem = j & 255, head = rem >> 4, rt = rem & 15;
      src = ((tno == 0) ? P.Wq : (tno == 1) ? P.Wk : P.Wv) + head * 65536;
      dst = ((tno == 0) ? P.WqT : (tno == 1) ? P.WkT : P.WvT) + head * 65536;
      C = 64; r0 = rt * 64; c0 = 0;
    } else {
      int j2 = j - 768;
      src = P.Wo; dst = P.WoT; C = 1024;
      r0 = (j2 & 15) * 64; c0 = (j2 >> 4) * 64;
    }
    int tx = tid & 63, ty = tid >> 6;
    __syncthreads();   // protect sm.t against previous loop iteration's reads
    #pragma unroll
    for(int i2 = 0; i2 < 64; i2 += 4)
      sm.t[ty + i2][tx] = src[(size_t)(r0 + ty + i2) * C + c0 + tx];
    __syncthreads();
    #pragma unroll
    for(int i2 = 0; i2 < 64; i2 += 4)
      dst[(size_t)(c0 + ty + i2) * 1024 + r0 + tx] = f2b(sm.t[tx][ty + i2]);
  }
}

// ---------------- shared GEMM core: C = A @ Bt^T, K=1024, BN=128, BK=64 ------
template<int BM>
DEVI void gemm_core(int mode, const u16* __restrict__ A, const u16* __restrict__ Bt,
                    const float* __restrict__ bias, void* __restrict__ Cp,
                    int m0, int n0, u16* sAb, u16* sBb){
  const int tid = threadIdx.x, w = tid >> 6, l = tid & 63;
  const int wr = w >> 1, wc = w & 1;
  constexpr int MI = BM / 32;
  f32x4 acc[MI][4];
  #pragma unroll
  for(int a = 0; a < MI; a++)
    #pragma unroll
    for(int b = 0; b < 4; b++) acc[a][b] = (f32x4){0.f, 0.f, 0.f, 0.f};

  const int NT = 16;  // K = 1024 / BK = 64
  auto STAGE = [&](int buf, int t){
    #pragma unroll
    for(int s2 = 0; s2 < BM / 32; s2++){
      int s = (BM / 32) * w + s2;
      int r = s * 8 + (l >> 3);
      int ch = (l & 7) ^ (r & 7);
      gload16((const char*)A + ((size_t)(m0 + r) * 1024 + t * 64) * 2 + ch * 16,
              (char*)(sAb + (size_t)buf * BM * 64) + s * 1024 + l * 16);
    }
    #pragma unroll
    for(int s2 = 0; s2 < 4; s2++){
      int s = 4 * w + s2;
      int r = s * 8 + (l >> 3);
      int ch = (l & 7) ^ (r & 7);
      gload16((const char*)Bt + ((size_t)(n0 + r) * 1024 + t * 64) * 2 + ch * 16,
              (char*)(sBb + (size_t)buf * 8192) + s * 1024 + l * 16);
    }
  };
  STAGE(0, 0);
  __syncthreads();
  for(int t = 0; t < NT; t++){
    const int cur = t & 1;
    if(t + 1 < NT) STAGE(cur ^ 1, t + 1);
    const char* pa = (const char*)(sAb + (size_t)cur * BM * 64);
    const char* pb = (const char*)(sBb + (size_t)cur * 8192);
    s16x8 af[MI][2], bf[4][2];
    #pragma unroll
    for(int mi = 0; mi < MI; mi++){
      int r = (BM / 2) * wr + 16 * mi + (l & 15);
      #pragma unroll
      for(int kk = 0; kk < 2; kk++)
        af[mi][kk] = *(const s16x8*)(pa + r * 128 + ((kk * 64 + 16 * (l >> 4)) ^ ((r & 7) << 4)));
    }
    #pragma unroll
    for(int ni = 0; ni < 4; ni++){
      int r = 64 * wc + 16 * ni + (l & 15);
      #pragma unroll
      for(int kk = 0; kk < 2; kk++)
        bf[ni][kk] = *(const s16x8*)(pb + r * 128 + ((kk * 64 + 16 * (l >> 4)) ^ ((r & 7) << 4)));
    }
    #pragma unroll
    for(int kk = 0; kk < 2; kk++)
      #pragma unroll
      for(int mi = 0; mi < MI; mi++)
        #pragma unroll
        for(int ni = 0; ni < 4; ni++)
          acc[mi][ni] = MFMA(af[mi][kk], bf[ni][kk], acc[mi][ni]);
    __syncthreads();
  }
  #pragma unroll
  for(int mi = 0; mi < MI; mi++){
    #pragma unroll
    for(int ni = 0; ni < 4; ni++){
      #pragma unroll
      for(int i = 0; i < 4; i++){
        int gr = m0 + (BM / 2) * wr + 16 * mi + 4 * (l >> 4) + i;
        int gc = n0 + 64 * wc + 16 * ni + (l & 15);
        float v = acc[mi][ni][i];
        if(mode == 0){
          ((u16*)Cp)[(size_t)gr * 1024 + gc] = f2b(v + bias[gc]);
        } else if(mode == 1){
          ((u16*)Cp)[((size_t)(gc >> 10) << 20) + ((size_t)gr << 10) + (gc & 1023)] =
              f2b(v + bias[gr]);
        } else {
          ((float*)Cp)[(size_t)gr * 1024 + gc] = v + bias[gc];
        }
      }
    }
  }
}

// ---------------- phase 2 unit: projections (768 raw units) ------------------
DEVI void proj_unit(const MP& P, SMem& sm, int raw){
  const int bid = (raw & 7) * 96 + (raw >> 3);   // XCD-contiguous chunks
  if(bid < 256){
    gemm_core<128>(0, P.Qb, P.WqT, P.bq, P.qw, (bid >> 3) * 128, (bid & 7) * 128,
                   sm.g.A, sm.g.B);
  } else if(bid < 512){
    int b2 = bid - 256;
    gemm_core<128>(0, P.Kb, P.WkT, P.bk, P.kw, (b2 >> 3) * 128, (b2 & 7) * 128,
                   sm.g.A, sm.g.B);
  } else {
    int b2 = bid - 512;
    gemm_core<128>(1, P.WvT, P.Vb, P.bv, P.vT, (b2 >> 5) * 128, (b2 & 31) * 128,
                   sm.g.A, sm.g.B);
  }
}

// ---------------- phase 4 unit: output projection (512 raw units) ------------
DEVI void final_u(const MP& P, SMem& sm, int raw){
  const int bid = (raw & 7) * 64 + (raw >> 3);
  gemm_core<64>(2, P.cc, P.WoT, P.bo, P.out, (bid >> 3) * 64, (bid & 7) * 128,
                sm.g.A, sm.g.B);
}

// ---------------- phase 3 unit: fused attention (1024 units) -----------------
// Two-pass (proven R2/R4 structure); attention written via LDS-staged P with
// vectorized f32x4 nontemporal stores (values bf16-rounded).
DEVI void attn_unit(const MP& P, SMem& sm, int u){
  u16* q_s = sm.at.q; u16* k_s = sm.at.k; u16* v_s = sm.at.v; u16* p_s = sm.at.p;
  const int tid = threadIdx.x, w = tid >> 6, l = tid & 63;
  const int bh = u & 63, qb = u >> 6, b = bh >> 4, h = bh & 15;
  const char* qg = (const char*)P.qw + ((size_t)(b * 1024 + qb * 64) * 1024 + h * 64) * 2;
  const char* kg = (const char*)P.kw + ((size_t)(b * 1024) * 1024 + h * 64) * 2;
  const char* vg = (const char*)P.vT + ((size_t)b * 1048576 + (size_t)h * 64 * 1024) * 2;
  float* ao = P.attn + (size_t)((h * 4 + b) * 1024 + qb * 64) * 1024;
  u16* cw = P.cc + (size_t)(b * 1024 + qb * 64) * 1024 + h * 64;

  // stage q tile [64][64]
  #pragma unroll
  for(int s2 = 0; s2 < 2; s2++){
    int s = 2 * w + s2;
    int r = s * 8 + (l >> 3);
    int ch = (l & 7) ^ (r & 7);
    gload16(qg + (size_t)r * 2048 + ch * 16, (char*)q_s + s * 1024 + l * 16);
  }

  const float KS = 0.18033688011112042f;  // log2(e)/8
  float rs[4] = {0.f, 0.f, 0.f, 0.f};
  s16x8 af0, af1;

  // ---- pass A: denominator sums ----
  for(int kt = 0; kt < 8; kt++){
    __syncthreads();
    #pragma unroll
    for(int s2 = 0; s2 < 4; s2++){
      int s = 4 * w + s2;
      int r = s * 8 + (l >> 3);
      int ch = (l & 7) ^ (r & 7);
      gload16(kg + (size_t)(kt * 128 + r) * 2048 + ch * 16, (char*)k_s + s * 1024 + l * 16);
    }
    __syncthreads();
    if(kt == 0){
      int rq = 16 * w + (l & 15);
      af0 = *(const s16x8*)((const char*)q_s + rq * 128 + ((16 * (l >> 4)) ^ ((rq & 7) << 4)));
      af1 = *(const s16x8*)((const char*)q_s + rq * 128 + ((64 + 16 * (l >> 4)) ^ ((rq & 7) << 4)));
    }
    #pragma unroll
    for(int f = 0; f < 8; f++){
      int r = 16 * f + (l & 15);
      s16x8 b0 = *(const s16x8*)((const char*)k_s + r * 128 + ((16 * (l >> 4)) ^ ((r & 7) << 4)));
      s16x8 b1 = *(const s16x8*)((const char*)k_s + r * 128 + ((64 + 16 * (l >> 4)) ^ ((r & 7) << 4)));
      f32x4 sf = (f32x4){0.f, 0.f, 0.f, 0.f};
      sf = MFMA(af0, b0, sf);
      sf = MFMA(af1, b1, sf);
      #pragma unroll
      for(int i = 0; i < 4; i++) rs[i] += exp2f(sf[i] * KS);
    }
  }
  #pragma unroll
  for(int i = 0; i < 4; i++){
    #pragma unroll
    for(int m = 1; m < 16; m <<= 1) rs[i] += __shfl_xor(rs[i], m, 64);
  }
  float inv[4];
  #pragma unroll
  for(int i = 0; i < 4; i++) inv[i] = 1.0f / rs[i];

  f32x4 oacc[4];
  #pragma unroll
  for(int fe = 0; fe < 4; fe++) oacc[fe] = (f32x4){0.f, 0.f, 0.f, 0.f};

  // ---- pass B: P->LDS, PV, vectorized attn writeback ----
  for(int kt = 0; kt < 8; kt++){
    __syncthreads();
    #pragma unroll
    for(int s2 = 0; s2 < 4; s2++){
      int s = 4 * w + s2;
      int r = s * 8 + (l >> 3);
      int ch = (l & 7) ^ (r & 7);
      gload16(kg + (size_t)(kt * 128 + r) * 2048 + ch * 16, (char*)k_s + s * 1024 + l * 16);
    }
    #pragma unroll
    for(int s2 = 0; s2 < 4; s2++){
      int s = 4 * w + s2;
      int e = s * 4 + (l >> 4);
      int ch = (l & 15) ^ (e & 15);
      gload16(vg + (size_t)e * 2048 + (size_t)kt * 256 + ch * 16, (char*)v_s + s * 1024 + l * 16);
    }
    __syncthreads();
    f32x4 sf[8];
    #pragma unroll
    for(int f = 0; f < 8; f++){
      int r = 16 * f + (l & 15);
      s16x8 b0 = *(const s16x8*)((const char*)k_s + r * 128 + ((16 * (l >> 4)) ^ ((r & 7) << 4)));
      s16x8 b1 = *(const s16x8*)((const char*)k_s + r * 128 + ((64 + 16 * (l >> 4)) ^ ((r & 7) << 4)));
      sf[f] = (f32x4){0.f, 0.f, 0.f, 0.f};
      sf[f] = MFMA(af0, b0, sf[f]);
      sf[f] = MFMA(af1, b1, sf[f]);
    }
    #pragma unroll
    for(int f = 0; f < 8; f++){
      #pragma unroll
      for(int i = 0; i < 4; i++){
        float p = exp2f(sf[f][i] * KS) * inv[i];
        int rr = 16 * w + 4 * (l >> 4) + i;
        *(u16*)((char*)p_s + rr * 256 + (((16 * f + (l & 15)) * 2) ^ ((rr & 15) << 4))) = f2b(p);
      }
    }
    __syncthreads();
    #pragma unroll
    for(int kc = 0; kc < 4; kc++){
      int rp = 16 * w + (l & 15);
      s16x8 pa = *(const s16x8*)((const char*)p_s + rp * 256 + ((kc * 64 + 16 * (l >> 4)) ^ ((rp & 15) << 4)));
      #pragma unroll
      for(int fe = 0; fe < 4; fe++){
        int e = 16 * fe + (l & 15);
        s16x8 bv = *(const s16x8*)((const char*)v_s + e * 256 + ((kc * 64 + 16 * (l >> 4)) ^ ((e & 15) << 4)));
        oacc[fe] = MFMA(pa, bv, oacc[fe]);
      }
    }
    // vectorized attention writeback from p_s (P already normalized)
    {
      const int rr2 = 16 * w + (l >> 2);
      const char* srow = (const char*)p_s + rr2 * 256;
      float* arow = ao + (size_t)rr2 * 1024 + kt * 128 + (l & 3) * 32;
      #pragma unroll
      for(int j = 0; j < 4; j++){
        int cb = (l & 3) * 64 + j * 16;
        s16x8 pv = *(const s16x8*)(srow + (cb ^ ((rr2 & 15) << 4)));
        f32x4 o0 = (f32x4){b2f((u16)pv[0]), b2f((u16)pv[1]),
                           b2f((u16)pv[2]), b2f((u16)pv[3])};
        f32x4 o1 = (f32x4){b2f((u16)pv[4]), b2f((u16)pv[5]),
                           b2f((u16)pv[6]), b2f((u16)pv[7])};
        __builtin_nontemporal_store(o0, (f32x4*)(arow + j * 8));
        __builtin_nontemporal_store(o1, (f32x4*)(arow + j * 8 + 4));
      }
    }
  }
  #pragma unroll
  for(int fe = 0; fe < 4; fe++){
    #pragma unroll
    for(int i = 0; i < 4; i++){
      int qi = 16 * w + 4 * (l >> 4) + i;
      cw[(size_t)qi * 1024 + 16 * fe + (l & 15)] = f2b(oacc[fe][i]);
    }
  }
}

// ---------------- the cooperative mega-kernel --------------------------------
__global__ __launch_bounds__(256, 2)
void k_mega(MP P){
  __shared__ SMem sm;
  cg::grid_group grid = cg::this_grid();
  const int bid = blockIdx.x;
  for(int u = bid; u < 13312; u += 512) prep_unit(P, sm, u);
  grid.sync();
  for(int u = bid; u < 768; u += 512) proj_unit(P, sm, u);
  grid.sync();
  for(int u = bid; u < 1024; u += 512) attn_unit(P, sm, u);
  grid.sync();
  final_u(P, sm, bid);
}

// ---------------- fallback wrappers (plain launches, same units) -------------
__global__ __launch_bounds__(256) void k_prep_w(MP P){
  __shared__ SMem sm; prep_unit(P, sm, blockIdx.x);
}
__global__ __launch_bounds__(256) void k_proj_w(MP P){
  __shared__ SMem sm; proj_unit(P, sm, blockIdx.x);
}
__global__ __launch_bounds__(256) void k_attn_w(MP P){
  __shared__ SMem sm; attn_unit(P, sm, blockIdx.x);
}
__global__ __launch_bounds__(256) void k_final_w(MP P){
  __shared__ SMem sm; final_u(P, sm, blockIdx.x);
}

// ---------------- host launch ------------------------------------------------
extern "C" void kernel_launch(void* const* d_in, const int* in_sizes, int n_in,
                              void* d_out, int out_size, void* d_ws, size_t ws_size,
                              hipStream_t stream){
  char* ws = (char*)d_ws;
  MP hp;
  hp.Q  = (const float*)d_in[0];
  hp.K  = (const float*)d_in[1];
  hp.V  = (const float*)d_in[2];
  hp.Wq = (const float*)d_in[3];
  hp.bq = (const float*)d_in[4];
  hp.Wk = (const float*)d_in[5];
  hp.bk = (const float*)d_in[6];
  hp.Wv = (const float*)d_in[7];
  hp.bv = (const float*)d_in[8];
  hp.Wo = (const float*)d_in[9];
  hp.bo = (const float*)d_in[10];
  hp.qw  = (u16*)(ws + 0);          // [4096][1024] bf16
  hp.kw  = (u16*)(ws + 8388608);
  hp.vT  = (u16*)(ws + 16777216);   // [b][h*64+e][1024]
  hp.cc  = (u16*)(ws + 25165824);   // concat
  hp.WqT = (u16*)(ws + 33554432);
  hp.WkT = (u16*)(ws + 35651584);
  hp.WvT = (u16*)(ws + 37748736);
  hp.WoT = (u16*)(ws + 39845888);
  // bf16 Q/K/V scratch lives in the not-yet-written attention region of d_out
  hp.Qb = (u16*)((char*)d_out + 16777216);
  hp.Kb = (u16*)((char*)d_out + 25165824);
  hp.Vb = (u16*)((char*)d_out + 33554432);
  hp.attn = (float*)d_out + 4194304;
  hp.out  = (float*)d_out;

  void* args[] = { (void*)&hp };
  hipError_t e = hipLaunchCooperativeKernel((const void*)k_mega, dim3(512),
                                            dim3(256), args, 0, stream);
  if(e != hipSuccess){
    // fallback: identical math as 4 plain kernels
    k_prep_w<<<13312, 256, 0, stream>>>(hp);
    k_proj_w<<<768, 256, 0, stream>>>(hp);
    k_attn_w<<<1024, 256, 0, stream>>>(hp);
    k_final_w<<<512, 256, 0, stream>>>(hp);
  }
}

// Round 7
// 728.824 us; speedup vs baseline: 1.0833x; 1.0833x over previous
//
#include <hip/hip_runtime.h>
#include <stdint.h>

#define DEVI __device__ __forceinline__
typedef unsigned short u16;
typedef __attribute__((ext_vector_type(8))) short s16x8;
typedef __attribute__((ext_vector_type(4))) float f32x4;

typedef __attribute__((address_space(1))) void as1_void;
typedef __attribute__((address_space(3))) void as3_void;

DEVI u16 f2b(float f){
  union { float f; uint32_t u; } x; x.f = f;
  return (u16)((x.u + 0x7fffu + ((x.u >> 16) & 1u)) >> 16);
}
DEVI float b2f(u16 u){
  union { uint32_t u; float f; } x; x.u = ((uint32_t)u) << 16;
  return x.f;
}
DEVI void gload16(const void* g, void* l){
  __builtin_amdgcn_global_load_lds((as1_void*)g, (as3_void*)l, 16, 0, 0);
}
DEVI f32x4 MFMA(s16x8 a, s16x8 b, f32x4 c){
  return __builtin_amdgcn_mfma_f32_16x16x32_bf16(a, b, c, 0, 0, 0);
}

// ---------------- K0: all prep in ONE launch (16.6 KB LDS, high occ) --------
__global__ __launch_bounds__(256)
void k_prep(const float* __restrict__ Q, const float* __restrict__ Kc,
            const float* __restrict__ V,
            u16* __restrict__ Qb, u16* __restrict__ Kb, u16* __restrict__ Vb,
            const float* __restrict__ Wq, const float* __restrict__ Wk,
            const float* __restrict__ Wv, const float* __restrict__ Wo,
            u16* __restrict__ WqT, u16* __restrict__ WkT,
            u16* __restrict__ WvT, u16* __restrict__ WoT){
  __shared__ float t[64][65];
  const int bid = blockIdx.x, tid = threadIdx.x;
  if(bid < 12288){
    int tno = bid >> 12;
    int blk = bid & 4095;
    const float* s = (tno == 0) ? Q : (tno == 1) ? Kc : V;
    u16* d = (tno == 0) ? Qb : (tno == 1) ? Kb : Vb;
    int i = (blk * 256 + tid) * 4;
    float4 v = *(const float4*)(s + i);
    ushort4 o;
    o.x = f2b(v.x); o.y = f2b(v.y); o.z = f2b(v.z); o.w = f2b(v.w);
    *(ushort4*)(d + i) = o;
  } else {
    int j = bid - 12288;
    const float* src; u16* dst; int C, r0, c0;
    if(j < 768){
      int tno = j >> 8, rem = j & 255, head = rem >> 4, rt = rem & 15;
      src = ((tno == 0) ? Wq : (tno == 1) ? Wk : Wv) + head * 65536;
      dst = ((tno == 0) ? WqT : (tno == 1) ? WkT : WvT) + head * 65536;
      C = 64; r0 = rt * 64; c0 = 0;
    } else {
      int j2 = j - 768;
      src = Wo; dst = WoT; C = 1024;
      r0 = (j2 & 15) * 64; c0 = (j2 >> 4) * 64;
    }
    int tx = tid & 63, ty = tid >> 6;
    #pragma unroll
    for(int i2 = 0; i2 < 64; i2 += 4)
      t[ty + i2][tx] = src[(size_t)(r0 + ty + i2) * C + c0 + tx];
    __syncthreads();
    #pragma unroll
    for(int i2 = 0; i2 < 64; i2 += 4)
      dst[(size_t)(c0 + ty + i2) * 1024 + r0 + tx] = f2b(t[tx][ty + i2]);
  }
}

// ------------ shared GEMM core: C = A @ Bt^T, K=1024, BN=128, param BK -------
// mode 0: bf16 out [M][1024], bias[col]
// mode 1: bf16 out at ((col>>10)<<20)+(row<<10)+(col&1023), bias[row]
// mode 2: fp32 out [M][1024], bias[col]
template<int BM, int BK>
DEVI void gemm_core(int mode, const u16* __restrict__ A, const u16* __restrict__ Bt,
                    const float* __restrict__ bias, void* __restrict__ Cp,
                    int m0, int n0, u16* sAb, u16* sBb){
  const int tid = threadIdx.x, w = tid >> 6, l = tid & 63;
  const int wr = w >> 1, wc = w & 1;
  constexpr int MI = BM / 32;          // A fragment tiles per wave (M side)
  constexpr int KK = BK / 32;          // K sub-steps per staged tile
  constexpr int CPR = BK / 8;          // 16B chunks per row
  constexpr int CPT_A = BM * BK / 2048;  // chunks per thread (A)
  constexpr int CPT_B = 128 * BK / 2048; // chunks per thread (B)
  constexpr int RB = 2 * BK;           // row bytes in LDS
  f32x4 acc[MI][4];
  #pragma unroll
  for(int a = 0; a < MI; a++)
    #pragma unroll
    for(int b = 0; b < 4; b++) acc[a][b] = (f32x4){0.f, 0.f, 0.f, 0.f};

  const int NT = 1024 / BK;
  auto STAGE = [&](int buf, int t){
    #pragma unroll
    for(int s2 = 0; s2 < CPT_A; s2++){
      int c = s2 * 256 + tid;
      int r = c / CPR, ch = (c % CPR) ^ (r & (CPR - 1));
      gload16((const char*)A + ((size_t)(m0 + r) * 1024 + t * BK) * 2 + ch * 16,
              (char*)sAb + (size_t)buf * BM * RB + c * 16);
    }
    #pragma unroll
    for(int s2 = 0; s2 < CPT_B; s2++){
      int c = s2 * 256 + tid;
      int r = c / CPR, ch = (c % CPR) ^ (r & (CPR - 1));
      gload16((const char*)Bt + ((size_t)(n0 + r) * 1024 + t * BK) * 2 + ch * 16,
              (char*)sBb + (size_t)buf * 128 * RB + c * 16);
    }
  };
  STAGE(0, 0);
  __syncthreads();
  for(int t = 0; t < NT; t++){
    const int cur = t & 1;
    if(t + 1 < NT) STAGE(cur ^ 1, t + 1);
    const char* pa = (const char*)sAb + (size_t)cur * BM * RB;
    const char* pb = (const char*)sBb + (size_t)cur * 128 * RB;
    s16x8 af[MI][KK], bf[4][KK];
    #pragma unroll
    for(int mi = 0; mi < MI; mi++){
      int r = (BM / 2) * wr + 16 * mi + (l & 15);
      #pragma unroll
      for(int kk = 0; kk < KK; kk++)
        af[mi][kk] = *(const s16x8*)(pa + r * RB +
                     ((kk * 64 + 16 * (l >> 4)) ^ ((r & (CPR - 1)) << 4)));
    }
    #pragma unroll
    for(int ni = 0; ni < 4; ni++){
      int r = 64 * wc + 16 * ni + (l & 15);
      #pragma unroll
      for(int kk = 0; kk < KK; kk++)
        bf[ni][kk] = *(const s16x8*)(pb + r * RB +
                     ((kk * 64 + 16 * (l >> 4)) ^ ((r & (CPR - 1)) << 4)));
    }
    #pragma unroll
    for(int kk = 0; kk < KK; kk++)
      #pragma unroll
      for(int mi = 0; mi < MI; mi++)
        #pragma unroll
        for(int ni = 0; ni < 4; ni++)
          acc[mi][ni] = MFMA(af[mi][kk], bf[ni][kk], acc[mi][ni]);
    __syncthreads();
  }
  #pragma unroll
  for(int mi = 0; mi < MI; mi++){
    #pragma unroll
    for(int ni = 0; ni < 4; ni++){
      #pragma unroll
      for(int i = 0; i < 4; i++){
        int gr = m0 + (BM / 2) * wr + 16 * mi + 4 * (l >> 4) + i;
        int gc = n0 + 64 * wc + 16 * ni + (l & 15);
        float v = acc[mi][ni][i];
        if(mode == 0){
          ((u16*)Cp)[(size_t)gr * 1024 + gc] = f2b(v + bias[gc]);
        } else if(mode == 1){
          ((u16*)Cp)[((size_t)(gc >> 10) << 20) + ((size_t)gr << 10) + (gc & 1023)] =
              f2b(v + bias[gr]);
        } else {
          ((float*)Cp)[(size_t)gr * 1024 + gc] = v + bias[gc];
        }
      }
    }
  }
}

// -------- K1: three projections, BK=32, 3 blocks/CU => all 768 resident ------
__global__ __launch_bounds__(256, 3)
void k_proj(const u16* __restrict__ Qb, const u16* __restrict__ Kb,
            const u16* __restrict__ Vb,
            const u16* __restrict__ WqT, const u16* __restrict__ WkT,
            const u16* __restrict__ WvT,
            const float* __restrict__ bq, const float* __restrict__ bk,
            const float* __restrict__ bv,
            u16* __restrict__ q_ws, u16* __restrict__ k_ws, u16* __restrict__ vT_ws){
  __shared__ u16 sA[2][128 * 32];
  __shared__ u16 sB[2][128 * 32];
  const int raw = blockIdx.x;
  const int bid = (raw & 7) * 96 + (raw >> 3);   // XCD-contiguous (768 % 8 == 0)
  if(bid < 256){
    gemm_core<128, 32>(0, Qb, WqT, bq, q_ws, (bid >> 3) * 128, (bid & 7) * 128,
                       &sA[0][0], &sB[0][0]);
  } else if(bid < 512){
    int b2 = bid - 256;
    gemm_core<128, 32>(0, Kb, WkT, bk, k_ws, (b2 >> 3) * 128, (b2 & 7) * 128,
                       &sA[0][0], &sB[0][0]);
  } else {
    int b2 = bid - 512;
    gemm_core<128, 32>(1, WvT, Vb, bv, vT_ws, (b2 >> 5) * 128, (b2 & 31) * 128,
                       &sA[0][0], &sB[0][0]);
  }
}

// ---------------- K3: output projection, BM=64/BK=64, XCD-swizzled -----------
__global__ __launch_bounds__(256)
void k_final(const u16* __restrict__ A, const u16* __restrict__ Bt,
             const float* __restrict__ bias, float* __restrict__ C){
  __shared__ u16 sA[2][64 * 64];
  __shared__ u16 sB[2][128 * 64];
  const int raw = blockIdx.x;
  const int bid = (raw & 7) * 64 + (raw >> 3);   // 512 % 8 == 0
  gemm_core<64, 64>(2, A, Bt, bias, C, (bid >> 3) * 64, (bid & 7) * 128,
                    &sA[0][0], &sB[0][0]);
}

// ---------------- K2: fused attention per (b,h,64-row q block) ---------------
// Two-pass (proven R2/R4); attention written via LDS-staged P with vectorized
// f32x4 nontemporal stores.
__global__ __launch_bounds__(256)
void k_attn(const u16* __restrict__ qws, const u16* __restrict__ kws,
            const u16* __restrict__ vws, float* __restrict__ attn,
            u16* __restrict__ concat){
  __shared__ u16 q_s[64 * 64];
  __shared__ u16 k_s[128 * 64];
  __shared__ u16 v_s[64 * 128];
  __shared__ u16 p_s[64 * 128];
  const int tid = threadIdx.x, w = tid >> 6, l = tid & 63;
  const int bx = blockIdx.x;
  const int bh = bx & 63, qb = bx >> 6, b = bh >> 4, h = bh & 15;
  const char* qg = (const char*)qws + ((size_t)(b * 1024 + qb * 64) * 1024 + h * 64) * 2;
  const char* kg = (const char*)kws + ((size_t)(b * 1024) * 1024 + h * 64) * 2;
  const char* vg = (const char*)vws + ((size_t)b * 1048576 + (size_t)h * 64 * 1024) * 2;
  float* ao = attn + (size_t)((h * 4 + b) * 1024 + qb * 64) * 1024;
  u16* cw = concat + (size_t)(b * 1024 + qb * 64) * 1024 + h * 64;

  // stage q tile [64][64]
  #pragma unroll
  for(int s2 = 0; s2 < 2; s2++){
    int s = 2 * w + s2;
    int r = s * 8 + (l >> 3);
    int ch = (l & 7) ^ (r & 7);
    gload16(qg + (size_t)r * 2048 + ch * 16, (char*)q_s + s * 1024 + l * 16);
  }

  const float KS = 0.18033688011112042f;  // log2(e)/8
  float rs[4] = {0.f, 0.f, 0.f, 0.f};
  s16x8 af0, af1;

  // ---- pass A: denominator sums ----
  for(int kt = 0; kt < 8; kt++){
    __syncthreads();
    #pragma unroll
    for(int s2 = 0; s2 < 4; s2++){
      int s = 4 * w + s2;
      int r = s * 8 + (l >> 3);
      int ch = (l & 7) ^ (r & 7);
      gload16(kg + (size_t)(kt * 128 + r) * 2048 + ch * 16, (char*)k_s + s * 1024 + l * 16);
    }
    __syncthreads();
    if(kt == 0){
      int rq = 16 * w + (l & 15);
      af0 = *(const s16x8*)((const char*)q_s + rq * 128 + ((16 * (l >> 4)) ^ ((rq & 7) << 4)));
      af1 = *(const s16x8*)((const char*)q_s + rq * 128 + ((64 + 16 * (l >> 4)) ^ ((rq & 7) << 4)));
    }
    #pragma unroll
    for(int f = 0; f < 8; f++){
      int r = 16 * f + (l & 15);
      s16x8 b0 = *(const s16x8*)((const char*)k_s + r * 128 + ((16 * (l >> 4)) ^ ((r & 7) << 4)));
      s16x8 b1 = *(const s16x8*)((const char*)k_s + r * 128 + ((64 + 16 * (l >> 4)) ^ ((r & 7) << 4)));
      f32x4 sf = (f32x4){0.f, 0.f, 0.f, 0.f};
      sf = MFMA(af0, b0, sf);
      sf = MFMA(af1, b1, sf);
      #pragma unroll
      for(int i = 0; i < 4; i++) rs[i] += exp2f(sf[i] * KS);
    }
  }
  #pragma unroll
  for(int i = 0; i < 4; i++){
    #pragma unroll
    for(int m = 1; m < 16; m <<= 1) rs[i] += __shfl_xor(rs[i], m, 64);
  }
  float inv[4];
  #pragma unroll
  for(int i = 0; i < 4; i++) inv[i] = 1.0f / rs[i];

  f32x4 oacc[4];
  #pragma unroll
  for(int fe = 0; fe < 4; fe++) oacc[fe] = (f32x4){0.f, 0.f, 0.f, 0.f};

  // ---- pass B: P->LDS, PV, vectorized attn writeback ----
  for(int kt = 0; kt < 8; kt++){
    __syncthreads();
    #pragma unroll
    for(int s2 = 0; s2 < 4; s2++){
      int s = 4 * w + s2;
      int r = s * 8 + (l >> 3);
      int ch = (l & 7) ^ (r & 7);
      gload16(kg + (size_t)(kt * 128 + r) * 2048 + ch * 16, (char*)k_s + s * 1024 + l * 16);
    }
    #pragma unroll
    for(int s2 = 0; s2 < 4; s2++){
      int s = 4 * w + s2;
      int e = s * 4 + (l >> 4);
      int ch = (l & 15) ^ (e & 15);
      gload16(vg + (size_t)e * 2048 + (size_t)kt * 256 + ch * 16, (char*)v_s + s * 1024 + l * 16);
    }
    __syncthreads();
    f32x4 sf[8];
    #pragma unroll
    for(int f = 0; f < 8; f++){
      int r = 16 * f + (l & 15);
      s16x8 b0 = *(const s16x8*)((const char*)k_s + r * 128 + ((16 * (l >> 4)) ^ ((r & 7) << 4)));
      s16x8 b1 = *(const s16x8*)((const char*)k_s + r * 128 + ((64 + 16 * (l >> 4)) ^ ((r & 7) << 4)));
      sf[f] = (f32x4){0.f, 0.f, 0.f, 0.f};
      sf[f] = MFMA(af0, b0, sf[f]);
      sf[f] = MFMA(af1, b1, sf[f]);
    }
    #pragma unroll
    for(int f = 0; f < 8; f++){
      #pragma unroll
      for(int i = 0; i < 4; i++){
        float p = exp2f(sf[f][i] * KS) * inv[i];
        int rr = 16 * w + 4 * (l >> 4) + i;
        *(u16*)((char*)p_s + rr * 256 + (((16 * f + (l & 15)) * 2) ^ ((rr & 15) << 4))) = f2b(p);
      }
    }
    __syncthreads();
    #pragma unroll
    for(int kc = 0; kc < 4; kc++){
      int rp = 16 * w + (l & 15);
      s16x8 pa = *(const s16x8*)((const char*)p_s + rp * 256 + ((kc * 64 + 16 * (l >> 4)) ^ ((rp & 15) << 4)));
      #pragma unroll
      for(int fe = 0; fe < 4; fe++){
        int e = 16 * fe + (l & 15);
        s16x8 bv = *(const s16x8*)((const char*)v_s + e * 256 + ((kc * 64 + 16 * (l >> 4)) ^ ((e & 15) << 4)));
        oacc[fe] = MFMA(pa, bv, oacc[fe]);
      }
    }
    // vectorized attention writeback from p_s (P already normalized)
    {
      const int rr2 = 16 * w + (l >> 2);
      const char* srow = (const char*)p_s + rr2 * 256;
      float* arow = ao + (size_t)rr2 * 1024 + kt * 128 + (l & 3) * 32;
      #pragma unroll
      for(int j = 0; j < 4; j++){
        int cb = (l & 3) * 64 + j * 16;
        s16x8 pv = *(const s16x8*)(srow + (cb ^ ((rr2 & 15) << 4)));
        f32x4 o0 = (f32x4){b2f((u16)pv[0]), b2f((u16)pv[1]),
                           b2f((u16)pv[2]), b2f((u16)pv[3])};
        f32x4 o1 = (f32x4){b2f((u16)pv[4]), b2f((u16)pv[5]),
                           b2f((u16)pv[6]), b2f((u16)pv[7])};
        __builtin_nontemporal_store(o0, (f32x4*)(arow + j * 8));
        __builtin_nontemporal_store(o1, (f32x4*)(arow + j * 8 + 4));
      }
    }
  }
  #pragma unroll
  for(int fe = 0; fe < 4; fe++){
    #pragma unroll
    for(int i = 0; i < 4; i++){
      int qi = 16 * w + 4 * (l >> 4) + i;
      cw[(size_t)qi * 1024 + 16 * fe + (l & 15)] = f2b(oacc[fe][i]);
    }
  }
}

// ---------------- host launch ------------------------------------------------
extern "C" void kernel_launch(void* const* d_in, const int* in_sizes, int n_in,
                              void* d_out, int out_size, void* d_ws, size_t ws_size,
                              hipStream_t stream){
  const float* Q  = (const float*)d_in[0];
  const float* Kc = (const float*)d_in[1];
  const float* V  = (const float*)d_in[2];
  const float* Wq = (const float*)d_in[3];
  const float* bq = (const float*)d_in[4];
  const float* Wk = (const float*)d_in[5];
  const float* bk = (const float*)d_in[6];
  const float* Wv = (const float*)d_in[7];
  const float* bv = (const float*)d_in[8];
  const float* Wo = (const float*)d_in[9];
  const float* bo = (const float*)d_in[10];
  float* out = (float*)d_out;

  char* ws = (char*)d_ws;
  u16* q_ws      = (u16*)(ws + 0);         // [4096][1024] bf16
  u16* k_ws      = (u16*)(ws + 8388608);
  u16* vT_ws     = (u16*)(ws + 16777216);  // [b][h*64+e][1024]
  u16* concat_ws = (u16*)(ws + 25165824);
  u16* WqT = (u16*)(ws + 33554432);
  u16* WkT = (u16*)(ws + 35651584);
  u16* WvT = (u16*)(ws + 37748736);
  u16* WoT = (u16*)(ws + 39845888);

  // bf16 Q/K/V scratch in the not-yet-written attention region of d_out
  u16* Qb = (u16*)((char*)d_out + 16777216);
  u16* Kb = (u16*)((char*)d_out + 25165824);
  u16* Vb = (u16*)((char*)d_out + 33554432);
  float* attn = out + 4194304;

  k_prep<<<13312, 256, 0, stream>>>(Q, Kc, V, Qb, Kb, Vb,
                                    Wq, Wk, Wv, Wo, WqT, WkT, WvT, WoT);
  k_proj<<<768, 256, 0, stream>>>(Qb, Kb, Vb, WqT, WkT, WvT, bq, bk, bv,
                                  q_ws, k_ws, vT_ws);
  k_attn<<<1024, 256, 0, stream>>>(q_ws, k_ws, vT_ws, attn, concat_ws);
  k_final<<<512, 256, 0, stream>>>(concat_ws, WoT, bo, out);
}

// Round 8
// 166.446 us; speedup vs baseline: 4.7436x; 4.3787x over previous
//
#include <hip/hip_runtime.h>
#include <stdint.h>

#define DEVI __device__ __forceinline__
typedef unsigned short u16;
typedef __attribute__((ext_vector_type(8))) short s16x8;
typedef __attribute__((ext_vector_type(4))) float f32x4;

typedef __attribute__((address_space(1))) void as1_void;
typedef __attribute__((address_space(3))) void as3_void;

DEVI u16 f2b(float f){
  union { float f; uint32_t u; } x; x.f = f;
  return (u16)((x.u + 0x7fffu + ((x.u >> 16) & 1u)) >> 16);
}
DEVI float b2f(u16 u){
  union { uint32_t u; float f; } x; x.u = ((uint32_t)u) << 16;
  return x.f;
}
DEVI void gload16(const void* g, void* l){
  __builtin_amdgcn_global_load_lds((as1_void*)g, (as3_void*)l, 16, 0, 0);
}
DEVI f32x4 MFMA(s16x8 a, s16x8 b, f32x4 c){
  return __builtin_amdgcn_mfma_f32_16x16x32_bf16(a, b, c, 0, 0, 0);
}

// ---------------- K0: all prep in ONE launch (16.6 KB LDS, high occ) --------
__global__ __launch_bounds__(256)
void k_prep(const float* __restrict__ Q, const float* __restrict__ Kc,
            const float* __restrict__ V,
            u16* __restrict__ Qb, u16* __restrict__ Kb, u16* __restrict__ Vb,
            const float* __restrict__ Wq, const float* __restrict__ Wk,
            const float* __restrict__ Wv, const float* __restrict__ Wo,
            u16* __restrict__ WqT, u16* __restrict__ WkT,
            u16* __restrict__ WvT, u16* __restrict__ WoT){
  __shared__ float t[64][65];
  const int bid = blockIdx.x, tid = threadIdx.x;
  if(bid < 12288){
    int tno = bid >> 12;
    int blk = bid & 4095;
    const float* s = (tno == 0) ? Q : (tno == 1) ? Kc : V;
    u16* d = (tno == 0) ? Qb : (tno == 1) ? Kb : Vb;
    int i = (blk * 256 + tid) * 4;
    float4 v = *(const float4*)(s + i);
    ushort4 o;
    o.x = f2b(v.x); o.y = f2b(v.y); o.z = f2b(v.z); o.w = f2b(v.w);
    *(ushort4*)(d + i) = o;
  } else {
    int j = bid - 12288;
    const float* src; u16* dst; int C, r0, c0;
    if(j < 768){
      int tno = j >> 8, rem = j & 255, head = rem >> 4, rt = rem & 15;
      src = ((tno == 0) ? Wq : (tno == 1) ? Wk : Wv) + head * 65536;
      dst = ((tno == 0) ? WqT : (tno == 1) ? WkT : WvT) + head * 65536;
      C = 64; r0 = rt * 64; c0 = 0;
    } else {
      int j2 = j - 768;
      src = Wo; dst = WoT; C = 1024;
      r0 = (j2 & 15) * 64; c0 = (j2 >> 4) * 64;
    }
    int tx = tid & 63, ty = tid >> 6;
    #pragma unroll
    for(int i2 = 0; i2 < 64; i2 += 4)
      t[ty + i2][tx] = src[(size_t)(r0 + ty + i2) * C + c0 + tx];
    __syncthreads();
    #pragma unroll
    for(int i2 = 0; i2 < 64; i2 += 4)
      dst[(size_t)(c0 + ty + i2) * 1024 + r0 + tx] = f2b(t[tx][ty + i2]);
  }
}

// ------------ shared GEMM core: C = A @ Bt^T, K=1024, BN=128, param BK -------
// mode 0: bf16 out [M][1024], bias[col]
// mode 1: bf16 out at ((col>>10)<<20)+(row<<10)+(col&1023), bias[row]
// mode 2: fp32 out [M][1024], bias[col]
template<int BM, int BK>
DEVI void gemm_core(int mode, const u16* __restrict__ A, const u16* __restrict__ Bt,
                    const float* __restrict__ bias, void* __restrict__ Cp,
                    int m0, int n0, u16* sAb, u16* sBb){
  const int tid = threadIdx.x, w = tid >> 6, l = tid & 63;
  const int wr = w >> 1, wc = w & 1;
  constexpr int MI = BM / 32;
  constexpr int KK = BK / 32;
  constexpr int CPR = BK / 8;
  constexpr int CPT_A = BM * BK / 2048;
  constexpr int CPT_B = 128 * BK / 2048;
  constexpr int RB = 2 * BK;
  f32x4 acc[MI][4];
  #pragma unroll
  for(int a = 0; a < MI; a++)
    #pragma unroll
    for(int b = 0; b < 4; b++) acc[a][b] = (f32x4){0.f, 0.f, 0.f, 0.f};

  const int NT = 1024 / BK;
  auto STAGE = [&](int buf, int t){
    #pragma unroll
    for(int s2 = 0; s2 < CPT_A; s2++){
      int c = s2 * 256 + tid;
      int r = c / CPR, ch = (c % CPR) ^ (r & (CPR - 1));
      gload16((const char*)A + ((size_t)(m0 + r) * 1024 + t * BK) * 2 + ch * 16,
              (char*)sAb + (size_t)buf * BM * RB + c * 16);
    }
    #pragma unroll
    for(int s2 = 0; s2 < CPT_B; s2++){
      int c = s2 * 256 + tid;
      int r = c / CPR, ch = (c % CPR) ^ (r & (CPR - 1));
      gload16((const char*)Bt + ((size_t)(n0 + r) * 1024 + t * BK) * 2 + ch * 16,
              (char*)sBb + (size_t)buf * 128 * RB + c * 16);
    }
  };
  STAGE(0, 0);
  __syncthreads();
  for(int t = 0; t < NT; t++){
    const int cur = t & 1;
    if(t + 1 < NT) STAGE(cur ^ 1, t + 1);
    const char* pa = (const char*)sAb + (size_t)cur * BM * RB;
    const char* pb = (const char*)sBb + (size_t)cur * 128 * RB;
    s16x8 af[MI][KK], bf[4][KK];
    #pragma unroll
    for(int mi = 0; mi < MI; mi++){
      int r = (BM / 2) * wr + 16 * mi + (l & 15);
      #pragma unroll
      for(int kk = 0; kk < KK; kk++)
        af[mi][kk] = *(const s16x8*)(pa + r * RB +
                     ((kk * 64 + 16 * (l >> 4)) ^ ((r & (CPR - 1)) << 4)));
    }
    #pragma unroll
    for(int ni = 0; ni < 4; ni++){
      int r = 64 * wc + 16 * ni + (l & 15);
      #pragma unroll
      for(int kk = 0; kk < KK; kk++)
        bf[ni][kk] = *(const s16x8*)(pb + r * RB +
                     ((kk * 64 + 16 * (l >> 4)) ^ ((r & (CPR - 1)) << 4)));
    }
    #pragma unroll
    for(int kk = 0; kk < KK; kk++)
      #pragma unroll
      for(int mi = 0; mi < MI; mi++)
        #pragma unroll
        for(int ni = 0; ni < 4; ni++)
          acc[mi][ni] = MFMA(af[mi][kk], bf[ni][kk], acc[mi][ni]);
    __syncthreads();
  }
  #pragma unroll
  for(int mi = 0; mi < MI; mi++){
    #pragma unroll
    for(int ni = 0; ni < 4; ni++){
      #pragma unroll
      for(int i = 0; i < 4; i++){
        int gr = m0 + (BM / 2) * wr + 16 * mi + 4 * (l >> 4) + i;
        int gc = n0 + 64 * wc + 16 * ni + (l & 15);
        float v = acc[mi][ni][i];
        if(mode == 0){
          ((u16*)Cp)[(size_t)gr * 1024 + gc] = f2b(v + bias[gc]);
        } else if(mode == 1){
          ((u16*)Cp)[((size_t)(gc >> 10) << 20) + ((size_t)gr << 10) + (gc & 1023)] =
              f2b(v + bias[gr]);
        } else {
          ((float*)Cp)[(size_t)gr * 1024 + gc] = v + bias[gc];
        }
      }
    }
  }
}

// -------- K1: three projections, BK=32, 3 blocks/CU => all 768 resident ------
__global__ __launch_bounds__(256, 3)
void k_proj(const u16* __restrict__ Qb, const u16* __restrict__ Kb,
            const u16* __restrict__ Vb,
            const u16* __restrict__ WqT, const u16* __restrict__ WkT,
            const u16* __restrict__ WvT,
            const float* __restrict__ bq, const float* __restrict__ bk,
            const float* __restrict__ bv,
            u16* __restrict__ q_ws, u16* __restrict__ k_ws, u16* __restrict__ vT_ws){
  __shared__ u16 sA[2][128 * 32];
  __shared__ u16 sB[2][128 * 32];
  const int raw = blockIdx.x;
  const int bid = (raw & 7) * 96 + (raw >> 3);   // XCD-contiguous (768 % 8 == 0)
  if(bid < 256){
    gemm_core<128, 32>(0, Qb, WqT, bq, q_ws, (bid >> 3) * 128, (bid & 7) * 128,
                       &sA[0][0], &sB[0][0]);
  } else if(bid < 512){
    int b2 = bid - 256;
    gemm_core<128, 32>(0, Kb, WkT, bk, k_ws, (b2 >> 3) * 128, (b2 & 7) * 128,
                       &sA[0][0], &sB[0][0]);
  } else {
    int b2 = bid - 512;
    gemm_core<128, 32>(1, WvT, Vb, bv, vT_ws, (b2 >> 5) * 128, (b2 & 31) * 128,
                       &sA[0][0], &sB[0][0]);
  }
}

// ---------------- K3: output projection, BM=64/BK=64, XCD-swizzled -----------
__global__ __launch_bounds__(256)
void k_final(const u16* __restrict__ A, const u16* __restrict__ Bt,
             const float* __restrict__ bias, float* __restrict__ C){
  __shared__ u16 sA[2][64 * 64];
  __shared__ u16 sB[2][128 * 64];
  const int raw = blockIdx.x;
  const int bid = (raw & 7) * 64 + (raw >> 3);   // 512 % 8 == 0
  gemm_core<64, 64>(2, A, Bt, bias, C, (bid >> 3) * 64, (bid & 7) * 128,
                    &sA[0][0], &sB[0][0]);
}

// ---------------- K2: fused attention per (b,h,64-row q block) ---------------
// Two-pass (R2/R4 structure). Attention writeback: per kt tile, re-read P from
// p_s (4 bf16/lane) and store ONE f32x4 per lane — each half-wave emits a
// fully contiguous 512-B row segment (full sectors; no nt partial-write RMW).
__global__ __launch_bounds__(256)
void k_attn(const u16* __restrict__ qws, const u16* __restrict__ kws,
            const u16* __restrict__ vws, float* __restrict__ attn,
            u16* __restrict__ concat){
  __shared__ u16 q_s[64 * 64];
  __shared__ u16 k_s[128 * 64];
  __shared__ u16 v_s[64 * 128];
  __shared__ u16 p_s[64 * 128];
  const int tid = threadIdx.x, w = tid >> 6, l = tid & 63;
  const int bx = blockIdx.x;
  const int bh = bx & 63, qb = bx >> 6, b = bh >> 4, h = bh & 15;
  const char* qg = (const char*)qws + ((size_t)(b * 1024 + qb * 64) * 1024 + h * 64) * 2;
  const char* kg = (const char*)kws + ((size_t)(b * 1024) * 1024 + h * 64) * 2;
  const char* vg = (const char*)vws + ((size_t)b * 1048576 + (size_t)h * 64 * 1024) * 2;
  float* ao = attn + (size_t)((h * 4 + b) * 1024 + qb * 64) * 1024;
  u16* cw = concat + (size_t)(b * 1024 + qb * 64) * 1024 + h * 64;

  // stage q tile [64][64]
  #pragma unroll
  for(int s2 = 0; s2 < 2; s2++){
    int s = 2 * w + s2;
    int r = s * 8 + (l >> 3);
    int ch = (l & 7) ^ (r & 7);
    gload16(qg + (size_t)r * 2048 + ch * 16, (char*)q_s + s * 1024 + l * 16);
  }

  const float KS = 0.18033688011112042f;  // log2(e)/8
  float rs[4] = {0.f, 0.f, 0.f, 0.f};
  s16x8 af0, af1;

  // ---- pass A: denominator sums ----
  for(int kt = 0; kt < 8; kt++){
    __syncthreads();
    #pragma unroll
    for(int s2 = 0; s2 < 4; s2++){
      int s = 4 * w + s2;
      int r = s * 8 + (l >> 3);
      int ch = (l & 7) ^ (r & 7);
      gload16(kg + (size_t)(kt * 128 + r) * 2048 + ch * 16, (char*)k_s + s * 1024 + l * 16);
    }
    __syncthreads();
    if(kt == 0){
      int rq = 16 * w + (l & 15);
      af0 = *(const s16x8*)((const char*)q_s + rq * 128 + ((16 * (l >> 4)) ^ ((rq & 7) << 4)));
      af1 = *(const s16x8*)((const char*)q_s + rq * 128 + ((64 + 16 * (l >> 4)) ^ ((rq & 7) << 4)));
    }
    #pragma unroll
    for(int f = 0; f < 8; f++){
      int r = 16 * f + (l & 15);
      s16x8 b0 = *(const s16x8*)((const char*)k_s + r * 128 + ((16 * (l >> 4)) ^ ((r & 7) << 4)));
      s16x8 b1 = *(const s16x8*)((const char*)k_s + r * 128 + ((64 + 16 * (l >> 4)) ^ ((r & 7) << 4)));
      f32x4 sf = (f32x4){0.f, 0.f, 0.f, 0.f};
      sf = MFMA(af0, b0, sf);
      sf = MFMA(af1, b1, sf);
      #pragma unroll
      for(int i = 0; i < 4; i++) rs[i] += exp2f(sf[i] * KS);
    }
  }
  #pragma unroll
  for(int i = 0; i < 4; i++){
    #pragma unroll
    for(int m = 1; m < 16; m <<= 1) rs[i] += __shfl_xor(rs[i], m, 64);
  }
  float inv[4];
  #pragma unroll
  for(int i = 0; i < 4; i++) inv[i] = 1.0f / rs[i];

  f32x4 oacc[4];
  #pragma unroll
  for(int fe = 0; fe < 4; fe++) oacc[fe] = (f32x4){0.f, 0.f, 0.f, 0.f};

  // ---- pass B: P->LDS, PV, coalesced attn writeback ----
  for(int kt = 0; kt < 8; kt++){
    __syncthreads();
    #pragma unroll
    for(int s2 = 0; s2 < 4; s2++){
      int s = 4 * w + s2;
      int r = s * 8 + (l >> 3);
      int ch = (l & 7) ^ (r & 7);
      gload16(kg + (size_t)(kt * 128 + r) * 2048 + ch * 16, (char*)k_s + s * 1024 + l * 16);
    }
    #pragma unroll
    for(int s2 = 0; s2 < 4; s2++){
      int s = 4 * w + s2;
      int e = s * 4 + (l >> 4);
      int ch = (l & 15) ^ (e & 15);
      gload16(vg + (size_t)e * 2048 + (size_t)kt * 256 + ch * 16, (char*)v_s + s * 1024 + l * 16);
    }
    __syncthreads();
    f32x4 sf[8];
    #pragma unroll
    for(int f = 0; f < 8; f++){
      int r = 16 * f + (l & 15);
      s16x8 b0 = *(const s16x8*)((const char*)k_s + r * 128 + ((16 * (l >> 4)) ^ ((r & 7) << 4)));
      s16x8 b1 = *(const s16x8*)((const char*)k_s + r * 128 + ((64 + 16 * (l >> 4)) ^ ((r & 7) << 4)));
      sf[f] = (f32x4){0.f, 0.f, 0.f, 0.f};
      sf[f] = MFMA(af0, b0, sf[f]);
      sf[f] = MFMA(af1, b1, sf[f]);
    }
    #pragma unroll
    for(int f = 0; f < 8; f++){
      #pragma unroll
      for(int i = 0; i < 4; i++){
        float p = exp2f(sf[f][i] * KS) * inv[i];
        int rr = 16 * w + 4 * (l >> 4) + i;
        *(u16*)((char*)p_s + rr * 256 + (((16 * f + (l & 15)) * 2) ^ ((rr & 15) << 4))) = f2b(p);
      }
    }
    __syncthreads();
    #pragma unroll
    for(int kc = 0; kc < 4; kc++){
      int rp = 16 * w + (l & 15);
      s16x8 pa = *(const s16x8*)((const char*)p_s + rp * 256 + ((kc * 64 + 16 * (l >> 4)) ^ ((rp & 15) << 4)));
      #pragma unroll
      for(int fe = 0; fe < 4; fe++){
        int e = 16 * fe + (l & 15);
        s16x8 bv = *(const s16x8*)((const char*)v_s + e * 256 + ((kc * 64 + 16 * (l >> 4)) ^ ((e & 15) << 4)));
        oacc[fe] = MFMA(pa, bv, oacc[fe]);
      }
    }
    // coalesced attn writeback: half-wave = one row's 128-col chunk (512 B)
    #pragma unroll
    for(int it = 0; it < 8; it++){
      int row = 16 * w + 2 * it + (l >> 5);
      int cb = 8 * (l & 31);     // byte offset of 4 bf16 within the row
      uint2 pv = *(const uint2*)((const char*)p_s + row * 256 +
                                 (cb ^ ((row & 15) << 4)));
      f32x4 o;
      o[0] = b2f((u16)(pv.x & 0xffffu));
      o[1] = b2f((u16)(pv.x >> 16));
      o[2] = b2f((u16)(pv.y & 0xffffu));
      o[3] = b2f((u16)(pv.y >> 16));
      __builtin_nontemporal_store(
          o, (f32x4*)(ao + (size_t)row * 1024 + kt * 128 + (l & 31) * 4));
    }
  }
  #pragma unroll
  for(int fe = 0; fe < 4; fe++){
    #pragma unroll
    for(int i = 0; i < 4; i++){
      int qi = 16 * w + 4 * (l >> 4) + i;
      cw[(size_t)qi * 1024 + 16 * fe + (l & 15)] = f2b(oacc[fe][i]);
    }
  }
}

// ---------------- host launch ------------------------------------------------
extern "C" void kernel_launch(void* const* d_in, const int* in_sizes, int n_in,
                              void* d_out, int out_size, void* d_ws, size_t ws_size,
                              hipStream_t stream){
  const float* Q  = (const float*)d_in[0];
  const float* Kc = (const float*)d_in[1];
  const float* V  = (const float*)d_in[2];
  const float* Wq = (const float*)d_in[3];
  const float* bq = (const float*)d_in[4];
  const float* Wk = (const float*)d_in[5];
  const float* bk = (const float*)d_in[6];
  const float* Wv = (const float*)d_in[7];
  const float* bv = (const float*)d_in[8];
  const float* Wo = (const float*)d_in[9];
  const float* bo = (const float*)d_in[10];
  float* out = (float*)d_out;

  char* ws = (char*)d_ws;
  u16* q_ws      = (u16*)(ws + 0);         // [4096][1024] bf16
  u16* k_ws      = (u16*)(ws + 8388608);
  u16* vT_ws     = (u16*)(ws + 16777216);  // [b][h*64+e][1024]
  u16* concat_ws = (u16*)(ws + 25165824);
  u16* WqT = (u16*)(ws + 33554432);
  u16* WkT = (u16*)(ws + 35651584);
  u16* WvT = (u16*)(ws + 37748736);
  u16* WoT = (u16*)(ws + 39845888);

  // bf16 Q/K/V scratch in the not-yet-written attention region of d_out
  u16* Qb = (u16*)((char*)d_out + 16777216);
  u16* Kb = (u16*)((char*)d_out + 25165824);
  u16* Vb = (u16*)((char*)d_out + 33554432);
  float* attn = out + 4194304;

  k_prep<<<13312, 256, 0, stream>>>(Q, Kc, V, Qb, Kb, Vb,
                                    Wq, Wk, Wv, Wo, WqT, WkT, WvT, WoT);
  k_proj<<<768, 256, 0, stream>>>(Qb, Kb, Vb, WqT, WkT, WvT, bq, bk, bv,
                                  q_ws, k_ws, vT_ws);
  k_attn<<<1024, 256, 0, stream>>>(q_ws, k_ws, vT_ws, attn, concat_ws);
  k_final<<<512, 256, 0, stream>>>(concat_ws, WoT, bo, out);
}

// Round 9
// 160.640 us; speedup vs baseline: 4.9150x; 1.0361x over previous
//
#include <hip/hip_runtime.h>
#include <stdint.h>

#define DEVI __device__ __forceinline__
typedef unsigned short u16;
typedef __attribute__((ext_vector_type(8))) short s16x8;
typedef __attribute__((ext_vector_type(4))) float f32x4;

typedef __attribute__((address_space(1))) void as1_void;
typedef __attribute__((address_space(3))) void as3_void;

DEVI u16 f2b(float f){
  union { float f; uint32_t u; } x; x.f = f;
  return (u16)((x.u + 0x7fffu + ((x.u >> 16) & 1u)) >> 16);
}
DEVI float b2f(u16 u){
  union { uint32_t u; float f; } x; x.u = ((uint32_t)u) << 16;
  return x.f;
}
DEVI void gload16(const void* g, void* l){
  __builtin_amdgcn_global_load_lds((as1_void*)g, (as3_void*)l, 16, 0, 0);
}
DEVI f32x4 MFMA(s16x8 a, s16x8 b, f32x4 c){
  return __builtin_amdgcn_mfma_f32_16x16x32_bf16(a, b, c, 0, 0, 0);
}

// ---------------- K0: all prep in ONE launch (16.6 KB LDS, high occ) --------
__global__ __launch_bounds__(256)
void k_prep(const float* __restrict__ Q, const float* __restrict__ Kc,
            const float* __restrict__ V,
            u16* __restrict__ Qb, u16* __restrict__ Kb, u16* __restrict__ Vb,
            const float* __restrict__ Wq, const float* __restrict__ Wk,
            const float* __restrict__ Wv, const float* __restrict__ Wo,
            u16* __restrict__ WqT, u16* __restrict__ WkT,
            u16* __restrict__ WvT, u16* __restrict__ WoT){
  __shared__ float t[64][65];
  const int bid = blockIdx.x, tid = threadIdx.x;
  if(bid < 12288){
    int tno = bid >> 12;
    int blk = bid & 4095;
    const float* s = (tno == 0) ? Q : (tno == 1) ? Kc : V;
    u16* d = (tno == 0) ? Qb : (tno == 1) ? Kb : Vb;
    int i = (blk * 256 + tid) * 4;
    float4 v = *(const float4*)(s + i);
    ushort4 o;
    o.x = f2b(v.x); o.y = f2b(v.y); o.z = f2b(v.z); o.w = f2b(v.w);
    *(ushort4*)(d + i) = o;
  } else {
    int j = bid - 12288;
    const float* src; u16* dst; int C, r0, c0;
    if(j < 768){
      int tno = j >> 8, rem = j & 255, head = rem >> 4, rt = rem & 15;
      src = ((tno == 0) ? Wq : (tno == 1) ? Wk : Wv) + head * 65536;
      dst = ((tno == 0) ? WqT : (tno == 1) ? WkT : WvT) + head * 65536;
      C = 64; r0 = rt * 64; c0 = 0;
    } else {
      int j2 = j - 768;
      src = Wo; dst = WoT; C = 1024;
      r0 = (j2 & 15) * 64; c0 = (j2 >> 4) * 64;
    }
    int tx = tid & 63, ty = tid >> 6;
    #pragma unroll
    for(int i2 = 0; i2 < 64; i2 += 4)
      t[ty + i2][tx] = src[(size_t)(r0 + ty + i2) * C + c0 + tx];
    __syncthreads();
    #pragma unroll
    for(int i2 = 0; i2 < 64; i2 += 4)
      dst[(size_t)(c0 + ty + i2) * 1024 + r0 + tx] = f2b(t[tx][ty + i2]);
  }
}

// ------------ shared GEMM core: C = A @ Bt^T, K=1024, BN=128, param BK -------
// mode 0: bf16 out [M][1024], bias[col]
// mode 1: bf16 out at ((col>>10)<<20)+(row<<10)+(col&1023), bias[row]
// mode 2: fp32 out [M][1024], bias[col]
template<int BM, int BK>
DEVI void gemm_core(int mode, const u16* __restrict__ A, const u16* __restrict__ Bt,
                    const float* __restrict__ bias, void* __restrict__ Cp,
                    int m0, int n0, u16* sAb, u16* sBb){
  const int tid = threadIdx.x, w = tid >> 6, l = tid & 63;
  const int wr = w >> 1, wc = w & 1;
  constexpr int MI = BM / 32;
  constexpr int KK = BK / 32;
  constexpr int CPR = BK / 8;
  constexpr int CPT_A = BM * BK / 2048;
  constexpr int CPT_B = 128 * BK / 2048;
  constexpr int RB = 2 * BK;
  f32x4 acc[MI][4];
  #pragma unroll
  for(int a = 0; a < MI; a++)
    #pragma unroll
    for(int b = 0; b < 4; b++) acc[a][b] = (f32x4){0.f, 0.f, 0.f, 0.f};

  const int NT = 1024 / BK;
  auto STAGE = [&](int buf, int t){
    #pragma unroll
    for(int s2 = 0; s2 < CPT_A; s2++){
      int c = s2 * 256 + tid;
      int r = c / CPR, ch = (c % CPR) ^ (r & (CPR - 1));
      gload16((const char*)A + ((size_t)(m0 + r) * 1024 + t * BK) * 2 + ch * 16,
              (char*)sAb + (size_t)buf * BM * RB + c * 16);
    }
    #pragma unroll
    for(int s2 = 0; s2 < CPT_B; s2++){
      int c = s2 * 256 + tid;
      int r = c / CPR, ch = (c % CPR) ^ (r & (CPR - 1));
      gload16((const char*)Bt + ((size_t)(n0 + r) * 1024 + t * BK) * 2 + ch * 16,
              (char*)sBb + (size_t)buf * 128 * RB + c * 16);
    }
  };
  STAGE(0, 0);
  __syncthreads();
  for(int t = 0; t < NT; t++){
    const int cur = t & 1;
    if(t + 1 < NT) STAGE(cur ^ 1, t + 1);
    const char* pa = (const char*)sAb + (size_t)cur * BM * RB;
    const char* pb = (const char*)sBb + (size_t)cur * 128 * RB;
    s16x8 af[MI][KK], bf[4][KK];
    #pragma unroll
    for(int mi = 0; mi < MI; mi++){
      int r = (BM / 2) * wr + 16 * mi + (l & 15);
      #pragma unroll
      for(int kk = 0; kk < KK; kk++)
        af[mi][kk] = *(const s16x8*)(pa + r * RB +
                     ((kk * 64 + 16 * (l >> 4)) ^ ((r & (CPR - 1)) << 4)));
    }
    #pragma unroll
    for(int ni = 0; ni < 4; ni++){
      int r = 64 * wc + 16 * ni + (l & 15);
      #pragma unroll
      for(int kk = 0; kk < KK; kk++)
        bf[ni][kk] = *(const s16x8*)(pb + r * RB +
                     ((kk * 64 + 16 * (l >> 4)) ^ ((r & (CPR - 1)) << 4)));
    }
    #pragma unroll
    for(int kk = 0; kk < KK; kk++)
      #pragma unroll
      for(int mi = 0; mi < MI; mi++)
        #pragma unroll
        for(int ni = 0; ni < 4; ni++)
          acc[mi][ni] = MFMA(af[mi][kk], bf[ni][kk], acc[mi][ni]);
    __syncthreads();
  }
  #pragma unroll
  for(int mi = 0; mi < MI; mi++){
    #pragma unroll
    for(int ni = 0; ni < 4; ni++){
      #pragma unroll
      for(int i = 0; i < 4; i++){
        int gr = m0 + (BM / 2) * wr + 16 * mi + 4 * (l >> 4) + i;
        int gc = n0 + 64 * wc + 16 * ni + (l & 15);
        float v = acc[mi][ni][i];
        if(mode == 0){
          ((u16*)Cp)[(size_t)gr * 1024 + gc] = f2b(v + bias[gc]);
        } else if(mode == 1){
          ((u16*)Cp)[((size_t)(gc >> 10) << 20) + ((size_t)gr << 10) + (gc & 1023)] =
              f2b(v + bias[gr]);
        } else {
          ((float*)Cp)[(size_t)gr * 1024 + gc] = v + bias[gc];
        }
      }
    }
  }
}

// -------- K1: three projections, BK=32, 3 blocks/CU => all 768 resident ------
__global__ __launch_bounds__(256, 3)
void k_proj(const u16* __restrict__ Qb, const u16* __restrict__ Kb,
            const u16* __restrict__ Vb,
            const u16* __restrict__ WqT, const u16* __restrict__ WkT,
            const u16* __restrict__ WvT,
            const float* __restrict__ bq, const float* __restrict__ bk,
            const float* __restrict__ bv,
            u16* __restrict__ q_ws, u16* __restrict__ k_ws, u16* __restrict__ vT_ws){
  __shared__ u16 sA[2][128 * 32];
  __shared__ u16 sB[2][128 * 32];
  const int raw = blockIdx.x;
  const int bid = (raw & 7) * 96 + (raw >> 3);   // XCD-contiguous (768 % 8 == 0)
  if(bid < 256){
    gemm_core<128, 32>(0, Qb, WqT, bq, q_ws, (bid >> 3) * 128, (bid & 7) * 128,
                       &sA[0][0], &sB[0][0]);
  } else if(bid < 512){
    int b2 = bid - 256;
    gemm_core<128, 32>(0, Kb, WkT, bk, k_ws, (b2 >> 3) * 128, (b2 & 7) * 128,
                       &sA[0][0], &sB[0][0]);
  } else {
    int b2 = bid - 512;
    gemm_core<128, 32>(1, WvT, Vb, bv, vT_ws, (b2 >> 5) * 128, (b2 & 31) * 128,
                       &sA[0][0], &sB[0][0]);
  }
}

// ---------------- K3: output projection, BM=64/BK=64, XCD-swizzled -----------
__global__ __launch_bounds__(256)
void k_final(const u16* __restrict__ A, const u16* __restrict__ Bt,
             const float* __restrict__ bias, float* __restrict__ C){
  __shared__ u16 sA[2][64 * 64];
  __shared__ u16 sB[2][128 * 64];
  const int raw = blockIdx.x;
  const int bid = (raw & 7) * 64 + (raw >> 3);   // 512 % 8 == 0
  gemm_core<64, 64>(2, A, Bt, bias, C, (bid >> 3) * 64, (bid & 7) * 128,
                    &sA[0][0], &sB[0][0]);
}

// ---------------- K2: fused attention, 40 KB LDS -> 4 blocks/CU --------------
// Q fragments in registers; 16 kv-tiles of 64 with dbuf K/V; P transpose via
// single p_s (intra-wave only: wave w owns rows 16w..16w+15 for write, A-frag
// read, and writeback). One barrier per tile; stage issued at top of the
// iteration so its latency hides under QK+exp+PV+writeback.
__global__ __launch_bounds__(256, 4)
void k_attn(const u16* __restrict__ qws, const u16* __restrict__ kws,
            const u16* __restrict__ vws, float* __restrict__ attn,
            u16* __restrict__ concat){
  __shared__ u16 k_s[2][64 * 64];   // 16 KB
  __shared__ u16 v_s[2][64 * 64];   // 16 KB
  __shared__ u16 p_s[64 * 64];      //  8 KB
  const int tid = threadIdx.x, w = tid >> 6, l = tid & 63;
  const int bx = blockIdx.x;
  const int bh = bx & 63, qb = bx >> 6, b = bh >> 4, h = bh & 15;
  const char* qg = (const char*)qws + ((size_t)(b * 1024 + qb * 64) * 1024 + h * 64) * 2;
  const char* kg = (const char*)kws + ((size_t)(b * 1024) * 1024 + h * 64) * 2;
  const char* vg = (const char*)vws + ((size_t)b * 1048576 + (size_t)h * 64 * 1024) * 2;
  float* ao = attn + (size_t)((h * 4 + b) * 1024 + qb * 64) * 1024;
  u16* cw = concat + (size_t)(b * 1024 + qb * 64) * 1024 + h * 64;

  // K tile [64 kv][64 e], rows 128 B = 8 chunks, LDS linear, src pre-swizzled
  auto STAGEK = [&](int buf, int kt){
    #pragma unroll
    for(int rd = 0; rd < 2; rd++){
      int c = rd * 256 + tid;
      int r = c >> 3, ch = c & 7;
      gload16(kg + (size_t)(kt * 64 + r) * 2048 + ((ch ^ (r & 7)) * 16),
              (char*)k_s[buf] + c * 16);
    }
  };
  // V tile [64 e][64 kv] from vT
  auto STAGEV = [&](int buf, int kt){
    #pragma unroll
    for(int rd = 0; rd < 2; rd++){
      int c = rd * 256 + tid;
      int e = c >> 3, ch = c & 7;
      gload16(vg + (size_t)e * 2048 + kt * 128 + ((ch ^ (e & 7)) * 16),
              (char*)v_s[buf] + c * 16);
    }
  };

  // Q fragments straight to registers (row rq, d 0..31 and 32..63)
  s16x8 af0, af1;
  {
    int rq = 16 * w + (l & 15);
    af0 = *(const s16x8*)(qg + (size_t)rq * 2048 + (l >> 4) * 16);
    af1 = *(const s16x8*)(qg + (size_t)rq * 2048 + 64 + (l >> 4) * 16);
  }

  const float KS = 0.18033688011112042f;  // log2(e)/8
  float rs[4] = {0.f, 0.f, 0.f, 0.f};

  // ---- pass A: denominator sums (K-only dbuf, 1 barrier/tile) ----
  STAGEK(0, 0);
  __syncthreads();
  for(int kt = 0; kt < 16; kt++){
    const int cur = kt & 1;
    if(kt + 1 < 16) STAGEK(cur ^ 1, kt + 1);
    #pragma unroll
    for(int f = 0; f < 4; f++){
      int r = 16 * f + (l & 15);
      s16x8 b0 = *(const s16x8*)((const char*)k_s[cur] + r * 128 + ((16 * (l >> 4)) ^ ((r & 7) << 4)));
      s16x8 b1 = *(const s16x8*)((const char*)k_s[cur] + r * 128 + ((64 + 16 * (l >> 4)) ^ ((r & 7) << 4)));
      f32x4 sf = (f32x4){0.f, 0.f, 0.f, 0.f};
      sf = MFMA(af0, b0, sf);
      sf = MFMA(af1, b1, sf);
      #pragma unroll
      for(int i = 0; i < 4; i++) rs[i] += exp2f(sf[i] * KS);
    }
    __syncthreads();
  }
  #pragma unroll
  for(int i = 0; i < 4; i++){
    #pragma unroll
    for(int m = 1; m < 16; m <<= 1) rs[i] += __shfl_xor(rs[i], m, 64);
  }
  float inv[4];
  #pragma unroll
  for(int i = 0; i < 4; i++) inv[i] = 1.0f / rs[i];

  f32x4 oacc[4];
  #pragma unroll
  for(int fe = 0; fe < 4; fe++) oacc[fe] = (f32x4){0.f, 0.f, 0.f, 0.f};

  // ---- pass B: QK -> P(normalized) -> p_s -> {PV, attn writeback} ----
  STAGEK(0, 0);
  STAGEV(0, 0);
  __syncthreads();
  for(int kt = 0; kt < 16; kt++){
    const int cur = kt & 1;
    if(kt + 1 < 16){ STAGEK(cur ^ 1, kt + 1); STAGEV(cur ^ 1, kt + 1); }
    // QK^T for this 64-kv tile
    f32x4 sf[4];
    #pragma unroll
    for(int f = 0; f < 4; f++){
      int r = 16 * f + (l & 15);
      s16x8 b0 = *(const s16x8*)((const char*)k_s[cur] + r * 128 + ((16 * (l >> 4)) ^ ((r & 7) << 4)));
      s16x8 b1 = *(const s16x8*)((const char*)k_s[cur] + r * 128 + ((64 + 16 * (l >> 4)) ^ ((r & 7) << 4)));
      sf[f] = (f32x4){0.f, 0.f, 0.f, 0.f};
      sf[f] = MFMA(af0, b0, sf[f]);
      sf[f] = MFMA(af1, b1, sf[f]);
    }
    // normalized P -> p_s (intra-wave rows 16w..16w+15)
    #pragma unroll
    for(int f = 0; f < 4; f++){
      #pragma unroll
      for(int i = 0; i < 4; i++){
        float p = exp2f(sf[f][i] * KS) * inv[i];
        int rr = 16 * w + 4 * (l >> 4) + i;
        int cc = 16 * f + (l & 15);
        *(u16*)((char*)p_s + rr * 128 + ((cc * 2) ^ ((rr & 7) << 4))) = f2b(p);
      }
    }
    // PV: A-frags from p_s (own wave rows), B-frags from v_s
    #pragma unroll
    for(int kc = 0; kc < 2; kc++){
      int rp = 16 * w + (l & 15);
      s16x8 pa = *(const s16x8*)((const char*)p_s + rp * 128 +
                  ((kc * 64 + 16 * (l >> 4)) ^ ((rp & 7) << 4)));
      #pragma unroll
      for(int fe = 0; fe < 4; fe++){
        int e = 16 * fe + (l & 15);
        s16x8 bv = *(const s16x8*)((const char*)v_s[cur] + e * 128 +
                    ((kc * 64 + 16 * (l >> 4)) ^ ((e & 7) << 4)));
        oacc[fe] = MFMA(pa, bv, oacc[fe]);
      }
    }
    // attn writeback from p_s: 16 lanes x f32x4 = one 256-B row segment
    #pragma unroll
    for(int it = 0; it < 4; it++){
      int row = 16 * w + 4 * it + (l >> 4);
      uint2 pv = *(const uint2*)((const char*)p_s + row * 128 +
                                 ((8 * (l & 15)) ^ ((row & 7) << 4)));
      f32x4 o;
      o[0] = b2f((u16)(pv.x & 0xffffu));
      o[1] = b2f((u16)(pv.x >> 16));
      o[2] = b2f((u16)(pv.y & 0xffffu));
      o[3] = b2f((u16)(pv.y >> 16));
      __builtin_nontemporal_store(
          o, (f32x4*)(ao + (size_t)row * 1024 + kt * 64 + (l & 15) * 4));
    }
    __syncthreads();
  }
  // concat epilogue
  #pragma unroll
  for(int fe = 0; fe < 4; fe++){
    #pragma unroll
    for(int i = 0; i < 4; i++){
      int qi = 16 * w + 4 * (l >> 4) + i;
      cw[(size_t)qi * 1024 + 16 * fe + (l & 15)] = f2b(oacc[fe][i]);
    }
  }
}

// ---------------- host launch ------------------------------------------------
extern "C" void kernel_launch(void* const* d_in, const int* in_sizes, int n_in,
                              void* d_out, int out_size, void* d_ws, size_t ws_size,
                              hipStream_t stream){
  const float* Q  = (const float*)d_in[0];
  const float* Kc = (const float*)d_in[1];
  const float* V  = (const float*)d_in[2];
  const float* Wq = (const float*)d_in[3];
  const float* bq = (const float*)d_in[4];
  const float* Wk = (const float*)d_in[5];
  const float* bk = (const float*)d_in[6];
  const float* Wv = (const float*)d_in[7];
  const float* bv = (const float*)d_in[8];
  const float* Wo = (const float*)d_in[9];
  const float* bo = (const float*)d_in[10];
  float* out = (float*)d_out;

  char* ws = (char*)d_ws;
  u16* q_ws      = (u16*)(ws + 0);         // [4096][1024] bf16
  u16* k_ws      = (u16*)(ws + 8388608);
  u16* vT_ws     = (u16*)(ws + 16777216);  // [b][h*64+e][1024]
  u16* concat_ws = (u16*)(ws + 25165824);
  u16* WqT = (u16*)(ws + 33554432);
  u16* WkT = (u16*)(ws + 35651584);
  u16* WvT = (u16*)(ws + 37748736);
  u16* WoT = (u16*)(ws + 39845888);

  // bf16 Q/K/V scratch in the not-yet-written attention region of d_out
  u16* Qb = (u16*)((char*)d_out + 16777216);
  u16* Kb = (u16*)((char*)d_out + 25165824);
  u16* Vb = (u16*)((char*)d_out + 33554432);
  float* attn = out + 4194304;

  k_prep<<<13312, 256, 0, stream>>>(Q, Kc, V, Qb, Kb, Vb,
                                    Wq, Wk, Wv, Wo, WqT, WkT, WvT, WoT);
  k_proj<<<768, 256, 0, stream>>>(Qb, Kb, Vb, WqT, WkT, WvT, bq, bk, bv,
                                  q_ws, k_ws, vT_ws);
  k_attn<<<1024, 256, 0, stream>>>(q_ws, k_ws, vT_ws, attn, concat_ws);
  k_final<<<512, 256, 0, stream>>>(concat_ws, WoT, bo, out);
}

// Round 10
// 158.421 us; speedup vs baseline: 4.9839x; 1.0140x over previous
//
#include <hip/hip_runtime.h>
#include <stdint.h>

#define DEVI __device__ __forceinline__
typedef unsigned short u16;
typedef __attribute__((ext_vector_type(8))) short s16x8;
typedef __attribute__((ext_vector_type(4))) float f32x4;

typedef __attribute__((address_space(1))) void as1_void;
typedef __attribute__((address_space(3))) void as3_void;

DEVI u16 f2b(float f){
  union { float f; uint32_t u; } x; x.f = f;
  return (u16)((x.u + 0x7fffu + ((x.u >> 16) & 1u)) >> 16);
}
DEVI float b2f(u16 u){
  union { uint32_t u; float f; } x; x.u = ((uint32_t)u) << 16;
  return x.f;
}
DEVI void gload16(const void* g, void* l){
  __builtin_amdgcn_global_load_lds((as1_void*)g, (as3_void*)l, 16, 0, 0);
}
DEVI f32x4 MFMA(s16x8 a, s16x8 b, f32x4 c){
  return __builtin_amdgcn_mfma_f32_16x16x32_bf16(a, b, c, 0, 0, 0);
}

// ---------------- K0: all prep in ONE launch (16.6 KB LDS, high occ) --------
__global__ __launch_bounds__(256)
void k_prep(const float* __restrict__ Q, const float* __restrict__ Kc,
            const float* __restrict__ V,
            u16* __restrict__ Qb, u16* __restrict__ Kb, u16* __restrict__ Vb,
            const float* __restrict__ Wq, const float* __restrict__ Wk,
            const float* __restrict__ Wv, const float* __restrict__ Wo,
            u16* __restrict__ WqT, u16* __restrict__ WkT,
            u16* __restrict__ WvT, u16* __restrict__ WoT){
  __shared__ float t[64][65];
  const int bid = blockIdx.x, tid = threadIdx.x;
  if(bid < 12288){
    int tno = bid >> 12;
    int blk = bid & 4095;
    const float* s = (tno == 0) ? Q : (tno == 1) ? Kc : V;
    u16* d = (tno == 0) ? Qb : (tno == 1) ? Kb : Vb;
    int i = (blk * 256 + tid) * 4;
    float4 v = *(const float4*)(s + i);
    ushort4 o;
    o.x = f2b(v.x); o.y = f2b(v.y); o.z = f2b(v.z); o.w = f2b(v.w);
    *(ushort4*)(d + i) = o;
  } else {
    int j = bid - 12288;
    const float* src; u16* dst; int C, r0, c0;
    if(j < 768){
      int tno = j >> 8, rem = j & 255, head = rem >> 4, rt = rem & 15;
      src = ((tno == 0) ? Wq : (tno == 1) ? Wk : Wv) + head * 65536;
      dst = ((tno == 0) ? WqT : (tno == 1) ? WkT : WvT) + head * 65536;
      C = 64; r0 = rt * 64; c0 = 0;
    } else {
      int j2 = j - 768;
      src = Wo; dst = WoT; C = 1024;
      r0 = (j2 & 15) * 64; c0 = (j2 >> 4) * 64;
    }
    int tx = tid & 63, ty = tid >> 6;
    #pragma unroll
    for(int i2 = 0; i2 < 64; i2 += 4)
      t[ty + i2][tx] = src[(size_t)(r0 + ty + i2) * C + c0 + tx];
    __syncthreads();
    #pragma unroll
    for(int i2 = 0; i2 < 64; i2 += 4)
      dst[(size_t)(c0 + ty + i2) * 1024 + r0 + tx] = f2b(t[tx][ty + i2]);
  }
}

// ------------ shared GEMM core: C = A @ Bt^T, K=1024, BN=128, param BK -------
// mode 0: bf16 out [M][1024], bias[col]
// mode 1: bf16 out at ((col>>10)<<20)+(row<<10)+(col&1023), bias[row]
// mode 2: fp32 out [M][1024], bias[col]
template<int BM, int BK>
DEVI void gemm_core(int mode, const u16* __restrict__ A, const u16* __restrict__ Bt,
                    const float* __restrict__ bias, void* __restrict__ Cp,
                    int m0, int n0, u16* sAb, u16* sBb){
  const int tid = threadIdx.x, w = tid >> 6, l = tid & 63;
  const int wr = w >> 1, wc = w & 1;
  constexpr int MI = BM / 32;
  constexpr int KK = BK / 32;
  constexpr int CPR = BK / 8;
  constexpr int CPT_A = BM * BK / 2048;
  constexpr int CPT_B = 128 * BK / 2048;
  constexpr int RB = 2 * BK;
  f32x4 acc[MI][4];
  #pragma unroll
  for(int a = 0; a < MI; a++)
    #pragma unroll
    for(int b = 0; b < 4; b++) acc[a][b] = (f32x4){0.f, 0.f, 0.f, 0.f};

  const int NT = 1024 / BK;
  auto STAGE = [&](int buf, int t){
    #pragma unroll
    for(int s2 = 0; s2 < CPT_A; s2++){
      int c = s2 * 256 + tid;
      int r = c / CPR, ch = (c % CPR) ^ (r & (CPR - 1));
      gload16((const char*)A + ((size_t)(m0 + r) * 1024 + t * BK) * 2 + ch * 16,
              (char*)sAb + (size_t)buf * BM * RB + c * 16);
    }
    #pragma unroll
    for(int s2 = 0; s2 < CPT_B; s2++){
      int c = s2 * 256 + tid;
      int r = c / CPR, ch = (c % CPR) ^ (r & (CPR - 1));
      gload16((const char*)Bt + ((size_t)(n0 + r) * 1024 + t * BK) * 2 + ch * 16,
              (char*)sBb + (size_t)buf * 128 * RB + c * 16);
    }
  };
  STAGE(0, 0);
  __syncthreads();
  for(int t = 0; t < NT; t++){
    const int cur = t & 1;
    if(t + 1 < NT) STAGE(cur ^ 1, t + 1);
    const char* pa = (const char*)sAb + (size_t)cur * BM * RB;
    const char* pb = (const char*)sBb + (size_t)cur * 128 * RB;
    s16x8 af[MI][KK], bf[4][KK];
    #pragma unroll
    for(int mi = 0; mi < MI; mi++){
      int r = (BM / 2) * wr + 16 * mi + (l & 15);
      #pragma unroll
      for(int kk = 0; kk < KK; kk++)
        af[mi][kk] = *(const s16x8*)(pa + r * RB +
                     ((kk * 64 + 16 * (l >> 4)) ^ ((r & (CPR - 1)) << 4)));
    }
    #pragma unroll
    for(int ni = 0; ni < 4; ni++){
      int r = 64 * wc + 16 * ni + (l & 15);
      #pragma unroll
      for(int kk = 0; kk < KK; kk++)
        bf[ni][kk] = *(const s16x8*)(pb + r * RB +
                     ((kk * 64 + 16 * (l >> 4)) ^ ((r & (CPR - 1)) << 4)));
    }
    #pragma unroll
    for(int kk = 0; kk < KK; kk++)
      #pragma unroll
      for(int mi = 0; mi < MI; mi++)
        #pragma unroll
        for(int ni = 0; ni < 4; ni++)
          acc[mi][ni] = MFMA(af[mi][kk], bf[ni][kk], acc[mi][ni]);
    __syncthreads();
  }
  #pragma unroll
  for(int mi = 0; mi < MI; mi++){
    #pragma unroll
    for(int ni = 0; ni < 4; ni++){
      #pragma unroll
      for(int i = 0; i < 4; i++){
        int gr = m0 + (BM / 2) * wr + 16 * mi + 4 * (l >> 4) + i;
        int gc = n0 + 64 * wc + 16 * ni + (l & 15);
        float v = acc[mi][ni][i];
        if(mode == 0){
          ((u16*)Cp)[(size_t)gr * 1024 + gc] = f2b(v + bias[gc]);
        } else if(mode == 1){
          ((u16*)Cp)[((size_t)(gc >> 10) << 20) + ((size_t)gr << 10) + (gc & 1023)] =
              f2b(v + bias[gr]);
        } else {
          ((float*)Cp)[(size_t)gr * 1024 + gc] = v + bias[gc];
        }
      }
    }
  }
}

// -------- K1: three projections, BK=32, 3 blocks/CU => all 768 resident ------
__global__ __launch_bounds__(256, 3)
void k_proj(const u16* __restrict__ Qb, const u16* __restrict__ Kb,
            const u16* __restrict__ Vb,
            const u16* __restrict__ WqT, const u16* __restrict__ WkT,
            const u16* __restrict__ WvT,
            const float* __restrict__ bq, const float* __restrict__ bk,
            const float* __restrict__ bv,
            u16* __restrict__ q_ws, u16* __restrict__ k_ws, u16* __restrict__ vT_ws){
  __shared__ u16 sA[2][128 * 32];
  __shared__ u16 sB[2][128 * 32];
  const int raw = blockIdx.x;
  const int bid = (raw & 7) * 96 + (raw >> 3);   // XCD-contiguous (768 % 8 == 0)
  if(bid < 256){
    gemm_core<128, 32>(0, Qb, WqT, bq, q_ws, (bid >> 3) * 128, (bid & 7) * 128,
                       &sA[0][0], &sB[0][0]);
  } else if(bid < 512){
    int b2 = bid - 256;
    gemm_core<128, 32>(0, Kb, WkT, bk, k_ws, (b2 >> 3) * 128, (b2 & 7) * 128,
                       &sA[0][0], &sB[0][0]);
  } else {
    int b2 = bid - 512;
    gemm_core<128, 32>(1, WvT, Vb, bv, vT_ws, (b2 >> 5) * 128, (b2 & 31) * 128,
                       &sA[0][0], &sB[0][0]);
  }
}

// ---------------- K3: output projection, BM=64/BK=64, XCD-swizzled -----------
__global__ __launch_bounds__(256)
void k_final(const u16* __restrict__ A, const u16* __restrict__ Bt,
             const float* __restrict__ bias, float* __restrict__ C){
  __shared__ u16 sA[2][64 * 64];
  __shared__ u16 sB[2][128 * 64];
  const int raw = blockIdx.x;
  const int bid = (raw & 7) * 64 + (raw >> 3);   // 512 % 8 == 0
  gemm_core<64, 64>(2, A, Bt, bias, C, (bid >> 3) * 64, (bid & 7) * 128,
                    &sA[0][0], &sB[0][0]);
}

// ---------------- K2: fused attention, 40 KB LDS -> 4 blocks/CU --------------
// Identical to round-9 EXCEPT: attention writeback uses REGULAR stores (L2
// write path, like the 6.9 TB/s fill kernel) instead of nontemporal. Clean A/B
// on the nt flag.
__global__ __launch_bounds__(256, 4)
void k_attn(const u16* __restrict__ qws, const u16* __restrict__ kws,
            const u16* __restrict__ vws, float* __restrict__ attn,
            u16* __restrict__ concat){
  __shared__ u16 k_s[2][64 * 64];   // 16 KB
  __shared__ u16 v_s[2][64 * 64];   // 16 KB
  __shared__ u16 p_s[64 * 64];      //  8 KB
  const int tid = threadIdx.x, w = tid >> 6, l = tid & 63;
  const int bx = blockIdx.x;
  const int bh = bx & 63, qb = bx >> 6, b = bh >> 4, h = bh & 15;
  const char* qg = (const char*)qws + ((size_t)(b * 1024 + qb * 64) * 1024 + h * 64) * 2;
  const char* kg = (const char*)kws + ((size_t)(b * 1024) * 1024 + h * 64) * 2;
  const char* vg = (const char*)vws + ((size_t)b * 1048576 + (size_t)h * 64 * 1024) * 2;
  float* ao = attn + (size_t)((h * 4 + b) * 1024 + qb * 64) * 1024;
  u16* cw = concat + (size_t)(b * 1024 + qb * 64) * 1024 + h * 64;

  auto STAGEK = [&](int buf, int kt){
    #pragma unroll
    for(int rd = 0; rd < 2; rd++){
      int c = rd * 256 + tid;
      int r = c >> 3, ch = c & 7;
      gload16(kg + (size_t)(kt * 64 + r) * 2048 + ((ch ^ (r & 7)) * 16),
              (char*)k_s[buf] + c * 16);
    }
  };
  auto STAGEV = [&](int buf, int kt){
    #pragma unroll
    for(int rd = 0; rd < 2; rd++){
      int c = rd * 256 + tid;
      int e = c >> 3, ch = c & 7;
      gload16(vg + (size_t)e * 2048 + kt * 128 + ((ch ^ (e & 7)) * 16),
              (char*)v_s[buf] + c * 16);
    }
  };

  // Q fragments straight to registers
  s16x8 af0, af1;
  {
    int rq = 16 * w + (l & 15);
    af0 = *(const s16x8*)(qg + (size_t)rq * 2048 + (l >> 4) * 16);
    af1 = *(const s16x8*)(qg + (size_t)rq * 2048 + 64 + (l >> 4) * 16);
  }

  const float KS = 0.18033688011112042f;  // log2(e)/8
  float rs[4] = {0.f, 0.f, 0.f, 0.f};

  // ---- pass A: denominator sums ----
  STAGEK(0, 0);
  __syncthreads();
  for(int kt = 0; kt < 16; kt++){
    const int cur = kt & 1;
    if(kt + 1 < 16) STAGEK(cur ^ 1, kt + 1);
    #pragma unroll
    for(int f = 0; f < 4; f++){
      int r = 16 * f + (l & 15);
      s16x8 b0 = *(const s16x8*)((const char*)k_s[cur] + r * 128 + ((16 * (l >> 4)) ^ ((r & 7) << 4)));
      s16x8 b1 = *(const s16x8*)((const char*)k_s[cur] + r * 128 + ((64 + 16 * (l >> 4)) ^ ((r & 7) << 4)));
      f32x4 sf = (f32x4){0.f, 0.f, 0.f, 0.f};
      sf = MFMA(af0, b0, sf);
      sf = MFMA(af1, b1, sf);
      #pragma unroll
      for(int i = 0; i < 4; i++) rs[i] += exp2f(sf[i] * KS);
    }
    __syncthreads();
  }
  #pragma unroll
  for(int i = 0; i < 4; i++){
    #pragma unroll
    for(int m = 1; m < 16; m <<= 1) rs[i] += __shfl_xor(rs[i], m, 64);
  }
  float inv[4];
  #pragma unroll
  for(int i = 0; i < 4; i++) inv[i] = 1.0f / rs[i];

  f32x4 oacc[4];
  #pragma unroll
  for(int fe = 0; fe < 4; fe++) oacc[fe] = (f32x4){0.f, 0.f, 0.f, 0.f};

  // ---- pass B: QK -> P(normalized) -> p_s -> {PV, attn writeback} ----
  STAGEK(0, 0);
  STAGEV(0, 0);
  __syncthreads();
  for(int kt = 0; kt < 16; kt++){
    const int cur = kt & 1;
    if(kt + 1 < 16){ STAGEK(cur ^ 1, kt + 1); STAGEV(cur ^ 1, kt + 1); }
    f32x4 sf[4];
    #pragma unroll
    for(int f = 0; f < 4; f++){
      int r = 16 * f + (l & 15);
      s16x8 b0 = *(const s16x8*)((const char*)k_s[cur] + r * 128 + ((16 * (l >> 4)) ^ ((r & 7) << 4)));
      s16x8 b1 = *(const s16x8*)((const char*)k_s[cur] + r * 128 + ((64 + 16 * (l >> 4)) ^ ((r & 7) << 4)));
      sf[f] = (f32x4){0.f, 0.f, 0.f, 0.f};
      sf[f] = MFMA(af0, b0, sf[f]);
      sf[f] = MFMA(af1, b1, sf[f]);
    }
    #pragma unroll
    for(int f = 0; f < 4; f++){
      #pragma unroll
      for(int i = 0; i < 4; i++){
        float p = exp2f(sf[f][i] * KS) * inv[i];
        int rr = 16 * w + 4 * (l >> 4) + i;
        int cc = 16 * f + (l & 15);
        *(u16*)((char*)p_s + rr * 128 + ((cc * 2) ^ ((rr & 7) << 4))) = f2b(p);
      }
    }
    #pragma unroll
    for(int kc = 0; kc < 2; kc++){
      int rp = 16 * w + (l & 15);
      s16x8 pa = *(const s16x8*)((const char*)p_s + rp * 128 +
                  ((kc * 64 + 16 * (l >> 4)) ^ ((rp & 7) << 4)));
      #pragma unroll
      for(int fe = 0; fe < 4; fe++){
        int e = 16 * fe + (l & 15);
        s16x8 bv = *(const s16x8*)((const char*)v_s[cur] + e * 128 +
                    ((kc * 64 + 16 * (l >> 4)) ^ ((e & 7) << 4)));
        oacc[fe] = MFMA(pa, bv, oacc[fe]);
      }
    }
    // attn writeback: REGULAR stores (A/B vs round 9's nontemporal)
    #pragma unroll
    for(int it = 0; it < 4; it++){
      int row = 16 * w + 4 * it + (l >> 4);
      uint2 pv = *(const uint2*)((const char*)p_s + row * 128 +
                                 ((8 * (l & 15)) ^ ((row & 7) << 4)));
      f32x4 o;
      o[0] = b2f((u16)(pv.x & 0xffffu));
      o[1] = b2f((u16)(pv.x >> 16));
      o[2] = b2f((u16)(pv.y & 0xffffu));
      o[3] = b2f((u16)(pv.y >> 16));
      *(f32x4*)(ao + (size_t)row * 1024 + kt * 64 + (l & 15) * 4) = o;
    }
    __syncthreads();
  }
  // concat epilogue
  #pragma unroll
  for(int fe = 0; fe < 4; fe++){
    #pragma unroll
    for(int i = 0; i < 4; i++){
      int qi = 16 * w + 4 * (l >> 4) + i;
      cw[(size_t)qi * 1024 + 16 * fe + (l & 15)] = f2b(oacc[fe][i]);
    }
  }
}

// ---------------- host launch ------------------------------------------------
extern "C" void kernel_launch(void* const* d_in, const int* in_sizes, int n_in,
                              void* d_out, int out_size, void* d_ws, size_t ws_size,
                              hipStream_t stream){
  const float* Q  = (const float*)d_in[0];
  const float* Kc = (const float*)d_in[1];
  const float* V  = (const float*)d_in[2];
  const float* Wq = (const float*)d_in[3];
  const float* bq = (const float*)d_in[4];
  const float* Wk = (const float*)d_in[5];
  const float* bk = (const float*)d_in[6];
  const float* Wv = (const float*)d_in[7];
  const float* bv = (const float*)d_in[8];
  const float* Wo = (const float*)d_in[9];
  const float* bo = (const float*)d_in[10];
  float* out = (float*)d_out;

  char* ws = (char*)d_ws;
  u16* q_ws      = (u16*)(ws + 0);         // [4096][1024] bf16
  u16* k_ws      = (u16*)(ws + 8388608);
  u16* vT_ws     = (u16*)(ws + 16777216);  // [b][h*64+e][1024]
  u16* concat_ws = (u16*)(ws + 25165824);
  u16* WqT = (u16*)(ws + 33554432);
  u16* WkT = (u16*)(ws + 35651584);
  u16* WvT = (u16*)(ws + 37748736);
  u16* WoT = (u16*)(ws + 39845888);

  // bf16 Q/K/V scratch in the not-yet-written attention region of d_out
  u16* Qb = (u16*)((char*)d_out + 16777216);
  u16* Kb = (u16*)((char*)d_out + 25165824);
  u16* Vb = (u16*)((char*)d_out + 33554432);
  float* attn = out + 4194304;

  k_prep<<<13312, 256, 0, stream>>>(Q, Kc, V, Qb, Kb, Vb,
                                    Wq, Wk, Wv, Wo, WqT, WkT, WvT, WoT);
  k_proj<<<768, 256, 0, stream>>>(Qb, Kb, Vb, WqT, WkT, WvT, bq, bk, bv,
                                  q_ws, k_ws, vT_ws);
  k_attn<<<1024, 256, 0, stream>>>(q_ws, k_ws, vT_ws, attn, concat_ws);
  k_final<<<512, 256, 0, stream>>>(concat_ws, WoT, bo, out);
}